// Round 1
// baseline (4013.478 us; speedup 1.0000x reference)
//
#include <hip/hip_runtime.h>

typedef unsigned int uint;
typedef unsigned short ushort;

// ---------- helpers ----------
__device__ __forceinline__ float silu_f(float t) { return t / (1.f + expf(-t)); }

__device__ __forceinline__ float bf2f(ushort u) {
  union { uint i; float f; } v; v.i = ((uint)u) << 16; return v.f;
}
__device__ __forceinline__ ushort f2bf(float f) {
  union { float f; uint i; } v; v.f = f;
  uint r = (v.i + 0x7fffu + ((v.i >> 16) & 1u)) >> 16;
  return (ushort)r;
}
__device__ __forceinline__ float4 fma4(float a, float4 b, float4 c) {
  c.x = fmaf(a, b.x, c.x); c.y = fmaf(a, b.y, c.y);
  c.z = fmaf(a, b.z, c.z); c.w = fmaf(a, b.w, c.w);
  return c;
}

// ---------- weight prep ----------
// src [J][K] row-major -> dst [Kpad][J], rows k>=K zero
__global__ __launch_bounds__(256) void transpose_pad(const float* __restrict__ src,
                                                     float* __restrict__ dst,
                                                     int J, int K, int Kpad) {
  int idx = blockIdx.x * 256 + threadIdx.x;
  if (idx >= Kpad * J) return;
  int k = idx / J, j = idx % J;
  dst[idx] = (k < K) ? src[j * K + k] : 0.f;
}

__global__ __launch_bounds__(256) void build_wqkvT(const float* __restrict__ wq,
                                                   const float* __restrict__ wk,
                                                   const float* __restrict__ wv,
                                                   float* __restrict__ dst) {
  int idx = blockIdx.x * 256 + threadIdx.x;   // 128*1536
  if (idx >= 128 * 1536) return;
  int k = idx / 1536, j = idx % 1536;
  float v;
  if (j < 512)       v = wq[j * 128 + k];
  else if (j < 1024) v = wk[(j - 512) * 128 + k];
  else               v = wv[(j - 1024) * 128 + k];
  dst[idx] = v;
}

// ---------- QKV GEMM: qkv[n][1536](bf16) = h[n][128] @ wqkvT + bias ----------
__global__ __launch_bounds__(256) void qkv_kernel(const float* __restrict__ h,
                                                  const float* __restrict__ wqkvT,
                                                  const float* __restrict__ bq,
                                                  const float* __restrict__ bk,
                                                  const float* __restrict__ bv,
                                                  ushort* __restrict__ qkv, int n) {
  __shared__ float As[64 * 68];
  __shared__ float Ws[64 * 64];
  int tid = threadIdx.x;
  int m0 = blockIdx.x * 64, jb = blockIdx.y * 64;
  int ty = tid >> 4, tx = tid & 15;
  float4 acc[4];
#pragma unroll
  for (int i = 0; i < 4; ++i) acc[i] = make_float4(0.f, 0.f, 0.f, 0.f);

  for (int kb = 0; kb < 2; ++kb) {
#pragma unroll
    for (int i = 0; i < 4; ++i) {
      int l = tid + i * 256;
      int row = l >> 4, c4 = l & 15;
      float4 v = make_float4(0.f, 0.f, 0.f, 0.f);
      if (m0 + row < n) v = *(const float4*)(h + (size_t)(m0 + row) * 128 + kb * 64 + c4 * 4);
      *(float4*)(As + row * 68 + c4 * 4) = v;
    }
#pragma unroll
    for (int i = 0; i < 4; ++i) {
      int l = tid + i * 256;
      int k = l >> 4, c4 = l & 15;
      *(float4*)(Ws + k * 64 + c4 * 4) =
          *(const float4*)(wqkvT + (size_t)(kb * 64 + k) * 1536 + jb + c4 * 4);
    }
    __syncthreads();
    for (int k = 0; k < 64; ++k) {
      float4 wv4 = *(const float4*)(Ws + k * 64 + tx * 4);
#pragma unroll
      for (int i = 0; i < 4; ++i) {
        float a = As[(ty * 4 + i) * 68 + k];
        acc[i] = fma4(a, wv4, acc[i]);
      }
    }
    __syncthreads();
  }
  int c = jb + tx * 4;
  float bb[4];
#pragma unroll
  for (int jj = 0; jj < 4; ++jj) {
    int col = c + jj;
    bb[jj] = (col < 512) ? bq[col] : (col < 1024) ? bk[col - 512] : bv[col - 1024];
  }
#pragma unroll
  for (int i = 0; i < 4; ++i) {
    int row = m0 + ty * 4 + i;
    if (row < n) {
      ushort4 st;
      st.x = f2bf(acc[i].x + bb[0]);
      st.y = f2bf(acc[i].y + bb[1]);
      st.z = f2bf(acc[i].z + bb[2]);
      st.w = f2bf(acc[i].w + bb[3]);
      *(ushort4*)(qkv + (size_t)row * 1536 + c) = st;
    }
  }
}

// ---------- fused edge MLP + pos-enc: scores[e][8] = pos_enc + edge_w ----------
#define TE 32
#define BSTRIDE 260

__global__ __launch_bounds__(256) void edge_mlp_kernel(
    const float* __restrict__ h, const float* __restrict__ x,
    const int* __restrict__ ei, int E,
    const float* __restrict__ ew1T, const float* __restrict__ eb1,
    const float* __restrict__ ew2T, const float* __restrict__ eb2,
    const float* __restrict__ eww, const float* __restrict__ ewb,
    const float* __restrict__ pw1T, const float* __restrict__ pb1,
    const float* __restrict__ pw2, const float* __restrict__ pb2,
    float* __restrict__ scores) {
  __shared__ float buf2[TE * BSTRIDE];
  __shared__ float geom[TE * 8];
  __shared__ float posout[TE * 8];
  __shared__ int irow[TE], icol[TE];
  int tid = threadIdx.x;
  int eb = blockIdx.x * TE;

  if (tid < TE) {
    int e = eb + tid; if (e >= E) e = E - 1;
    int r = ei[e], c = ei[E + e];
    irow[tid] = r; icol[tid] = c;
    float xr0 = x[r * 3 + 0], xr1 = x[r * 3 + 1], xr2 = x[r * 3 + 2];
    float xc0 = x[c * 3 + 0], xc1 = x[c * 3 + 1], xc2 = x[c * 3 + 2];
    float d0 = xr0 - xc0, d1 = xr1 - xc1, d2 = xr2 - xc2;
    geom[tid * 8 + 0] = d0 * d0 + d1 * d1 + d2 * d2;
    geom[tid * 8 + 1] = xr0; geom[tid * 8 + 2] = xr1; geom[tid * 8 + 3] = xr2;
    geom[tid * 8 + 4] = xc0; geom[tid * 8 + 5] = xc1; geom[tid * 8 + 6] = xc2;
    geom[tid * 8 + 7] = 0.f;
  }
  __syncthreads();

  // pos-enc layer1: tpos -> buf2[e][j]
  {
    int j = tid;
    float acc[TE];
    float b = pb1[j];
#pragma unroll
    for (int e = 0; e < TE; ++e) acc[e] = b;
#pragma unroll
    for (int k = 0; k < 6; ++k) {
      float wv = pw1T[k * 256 + j];
#pragma unroll
      for (int e = 0; e < TE; ++e) acc[e] = fmaf(geom[e * 8 + 1 + k], wv, acc[e]);
    }
#pragma unroll
    for (int e = 0; e < TE; ++e) buf2[e * BSTRIDE + j] = silu_f(acc[e]);
  }
  __syncthreads();
  // pos-enc layer2 -> posout[e][hh]
  {
    int e = tid >> 3, hh = tid & 7;
    float s = pb2[hh];
    for (int j = 0; j < 256; ++j)
      s = fmaf(buf2[e * BSTRIDE + j], pw2[hh * 256 + j], s);
    posout[e * 8 + hh] = s;
  }
  __syncthreads();

  int jg = tid & 63, eg = tid >> 6;
  int j0 = jg * 4, e0 = eg * 8;
  int re[8], ce[8];
#pragma unroll
  for (int ee = 0; ee < 8; ++ee) { re[ee] = irow[e0 + ee]; ce[ee] = icol[e0 + ee]; }

  float4 acc4[8];
  // edge MLP layer1 (K = 264 incl. zero pad): reads h directly (wave-uniform)
  {
    float4 b = *(const float4*)(eb1 + j0);
#pragma unroll
    for (int ee = 0; ee < 8; ++ee) acc4[ee] = b;
    for (int g = 0; g < 66; ++g) {
      const float4* wp = (const float4*)(ew1T + (size_t)g * 1024 + j0);
      float4 w0 = wp[0], w1 = wp[64], w2 = wp[128], w3 = wp[192];
#pragma unroll
      for (int ee = 0; ee < 8; ++ee) {
        float4 a;
        if (g < 32)      a = *(const float4*)(h + (size_t)re[ee] * 128 + g * 4);
        else if (g < 64) a = *(const float4*)(h + (size_t)ce[ee] * 128 + (g - 32) * 4);
        else             a = *(const float4*)(geom + (e0 + ee) * 8 + (g - 64) * 4);
        acc4[ee] = fma4(a.x, w0, acc4[ee]);
        acc4[ee] = fma4(a.y, w1, acc4[ee]);
        acc4[ee] = fma4(a.z, w2, acc4[ee]);
        acc4[ee] = fma4(a.w, w3, acc4[ee]);
      }
    }
  }
  // write t1 = silu(.) into buf2 (tpos fully consumed after sync above)
#pragma unroll
  for (int ee = 0; ee < 8; ++ee) {
    float4 v = acc4[ee];
    v.x = silu_f(v.x); v.y = silu_f(v.y); v.z = silu_f(v.z); v.w = silu_f(v.w);
    *(float4*)(buf2 + (e0 + ee) * BSTRIDE + j0) = v;
  }
  __syncthreads();
  // layer2
  {
    float4 b = *(const float4*)(eb2 + j0);
#pragma unroll
    for (int ee = 0; ee < 8; ++ee) acc4[ee] = b;
    for (int g = 0; g < 64; ++g) {
      const float4* wp = (const float4*)(ew2T + (size_t)g * 1024 + j0);
      float4 w0 = wp[0], w1 = wp[64], w2 = wp[128], w3 = wp[192];
#pragma unroll
      for (int ee = 0; ee < 8; ++ee) {
        float4 a = *(const float4*)(buf2 + (e0 + ee) * BSTRIDE + g * 4);
        acc4[ee] = fma4(a.x, w0, acc4[ee]);
        acc4[ee] = fma4(a.y, w1, acc4[ee]);
        acc4[ee] = fma4(a.z, w2, acc4[ee]);
        acc4[ee] = fma4(a.w, w3, acc4[ee]);
      }
    }
  }
  __syncthreads();   // everyone done reading t1
#pragma unroll
  for (int ee = 0; ee < 8; ++ee)
    *(float4*)(buf2 + (e0 + ee) * BSTRIDE + j0) = acc4[ee];   // t2 (no act)
  __syncthreads();
  // edge_w + combine
  {
    int e = tid >> 3, hh = tid & 7;
    float s = ewb[hh];
    for (int j = 0; j < 256; ++j)
      s = fmaf(buf2[e * BSTRIDE + j], eww[hh * 256 + j], s);
    s += posout[e * 8 + hh];
    if (eb + e < E) scores[(size_t)(eb + e) * 8 + hh] = s;
  }
}

// ---------- CSR build ----------
__global__ __launch_bounds__(256) void count_kernel(const int* __restrict__ ei,
                                                    int* __restrict__ cnt, int E) {
  int e = blockIdx.x * 256 + threadIdx.x;
  if (e < E) atomicAdd(&cnt[ei[e]], 1);
}

__global__ __launch_bounds__(1024) void scan_kernel(int* __restrict__ cnt,
                                                    int* __restrict__ offs, int n) {
  __shared__ int part[1024];
  int t = threadIdx.x;
  int chunk = (n + 1023) >> 10;
  int s = t * chunk, e = min(s + chunk, n);
  int sum = 0;
  for (int i = s; i < e; ++i) sum += cnt[i];
  part[t] = sum;
  __syncthreads();
  for (int off = 1; off < 1024; off <<= 1) {
    int v = (t >= off) ? part[t - off] : 0;
    __syncthreads();
    part[t] += v;
    __syncthreads();
  }
  int run = (t == 0) ? 0 : part[t - 1];
  for (int i = s; i < e; ++i) {
    int c = cnt[i];
    offs[i] = run;
    cnt[i] = run;     // becomes cursor
    run += c;
  }
  if (t == 1023) offs[n] = run;
}

__global__ __launch_bounds__(256) void fill_kernel(const int* __restrict__ ei,
                                                   int* __restrict__ cursor,
                                                   int* __restrict__ eidl, int E) {
  int e = blockIdx.x * 256 + threadIdx.x;
  if (e < E) {
    int p = atomicAdd(&cursor[ei[e]], 1);
    eidl[p] = e;
  }
}

// ---------- QK scores ----------
__device__ __forceinline__ float pairdot(uint a, uint b) {
  return bf2f((ushort)(a & 0xffffu)) * bf2f((ushort)(b & 0xffffu)) +
         bf2f((ushort)(a >> 16)) * bf2f((ushort)(b >> 16));
}

__global__ __launch_bounds__(256) void qk_kernel(const int* __restrict__ ei,
                                                 const int* __restrict__ mask,
                                                 const ushort* __restrict__ qkv,
                                                 float* __restrict__ scores, int E) {
  int idx = blockIdx.x * 256 + threadIdx.x;
  int e = idx >> 3, hh = idx & 7;
  if (e >= E) return;
  int r = ei[e], c = ei[E + e];
  const uint4* qp = (const uint4*)(qkv + (size_t)r * 1536 + hh * 64);
  const uint4* kp = (const uint4*)(qkv + (size_t)c * 1536 + 512 + hh * 64);
  float dot = 0.f;
#pragma unroll
  for (int i = 0; i < 8; ++i) {
    uint4 qa = qp[i];
    uint4 ka = kp[i];
    dot += pairdot(qa.x, ka.x) + pairdot(qa.y, ka.y) +
           pairdot(qa.z, ka.z) + pairdot(qa.w, ka.w);
  }
  float s = scores[idx];
  s = mask[e] ? (dot * 0.125f + s) : -1e9f;
  scores[idx] = s;
}

// ---------- per-node scatter softmax (in place on scores) ----------
__global__ __launch_bounds__(64) void softmax_kernel(const int* __restrict__ offs,
                                                     const int* __restrict__ eidl,
                                                     float* __restrict__ scores, int n) {
  int node = blockIdx.x;
  int start = offs[node], deg = offs[node + 1] - start;
  if (deg == 0) return;
  int l = threadIdx.x;
  int hh = l & 7, le = l >> 3;
  float m = -3.0e38f;
  for (int b = le; b < deg; b += 8) {
    int eid = eidl[start + b];
    m = fmaxf(m, scores[(size_t)eid * 8 + hh]);
  }
  m = fmaxf(m, __shfl_xor(m, 8));
  m = fmaxf(m, __shfl_xor(m, 16));
  m = fmaxf(m, __shfl_xor(m, 32));
  float ssum = 0.f;
  for (int b = le; b < deg; b += 8) {
    int eid = eidl[start + b];
    ssum += expf(scores[(size_t)eid * 8 + hh] - m);
  }
  ssum += __shfl_xor(ssum, 8);
  ssum += __shfl_xor(ssum, 16);
  ssum += __shfl_xor(ssum, 32);
  float inv = 1.f / (ssum + 1e-8f);
  for (int b = le; b < deg; b += 8) {
    int eid = eidl[start + b];
    size_t ix = (size_t)eid * 8 + hh;
    scores[ix] = expf(scores[ix] - m) * inv;
  }
}

// ---------- aggregation: agg[node][512] = sum attn * v[col] ----------
__global__ __launch_bounds__(512) void agg_kernel(const int* __restrict__ offs,
                                                  const int* __restrict__ eidl,
                                                  const int* __restrict__ ei,
                                                  const float* __restrict__ scores,
                                                  const ushort* __restrict__ qkv,
                                                  float* __restrict__ agg, int n, int E) {
  int node = blockIdx.x;
  int d = threadIdx.x;
  int start = offs[node], end = offs[node + 1];
  float acc = 0.f;
  for (int i = start; i < end; ++i) {
    int eid = eidl[i];
    int c = ei[E + eid];
    float a = scores[(size_t)eid * 8 + (d >> 6)];
    float v = bf2f(qkv[(size_t)c * 1536 + 1024 + d]);
    acc = fmaf(a, v, acc);
  }
  agg[(size_t)node * 512 + d] = acc;
}

// ---------- coord MLP (8 nodes/block), writes base (coord + bo) into d_out ----------
__global__ __launch_bounds__(256) void coord_kernel(
    const float* __restrict__ x,
    const float* __restrict__ cw1T, const float* __restrict__ cb1,
    const float* __restrict__ cw2T, const float* __restrict__ cb2,
    const float* __restrict__ cw3T, const float* __restrict__ cb3,
    const float* __restrict__ bo, float* __restrict__ out, int n) {
  __shared__ float c1[8 * 256];
  __shared__ float c2[8 * 256];
  int j = threadIdx.x;
  int n0 = blockIdx.x * 8;
  float w0 = cw1T[j], w1 = cw1T[256 + j], w2 = cw1T[512 + j], b1 = cb1[j];
#pragma unroll
  for (int nn = 0; nn < 8; ++nn) {
    int node = min(n0 + nn, n - 1);
    float t = fmaf(x[node * 3 + 2], w2,
              fmaf(x[node * 3 + 1], w1, fmaf(x[node * 3 + 0], w0, b1)));
    c1[nn * 256 + j] = silu_f(t);
  }
  __syncthreads();
  {
    float acc[8];
    float b2 = cb2[j];
#pragma unroll
    for (int nn = 0; nn < 8; ++nn) acc[nn] = b2;
    for (int k = 0; k < 256; ++k) {
      float wv = cw2T[k * 256 + j];
#pragma unroll
      for (int nn = 0; nn < 8; ++nn) acc[nn] = fmaf(c1[nn * 256 + k], wv, acc[nn]);
    }
#pragma unroll
    for (int nn = 0; nn < 8; ++nn) c2[nn * 256 + j] = silu_f(acc[nn]);
  }
  __syncthreads();
  if (j < 128) {
    float acc[8];
    float b3 = cb3[j] + bo[j];
#pragma unroll
    for (int nn = 0; nn < 8; ++nn) acc[nn] = b3;
    for (int k = 0; k < 256; ++k) {
      float wv = cw3T[k * 128 + j];
#pragma unroll
      for (int nn = 0; nn < 8; ++nn) acc[nn] = fmaf(c2[nn * 256 + k], wv, acc[nn]);
    }
#pragma unroll
    for (int nn = 0; nn < 8; ++nn) {
      int node = n0 + nn;
      if (node < n) out[(size_t)node * 128 + j] = acc[nn];
    }
  }
}

// ---------- out GEMM: out[n][128] += agg[n][512] @ woT ----------
__global__ __launch_bounds__(256) void out_gemm_kernel(const float* __restrict__ agg,
                                                       const float* __restrict__ woT,
                                                       float* __restrict__ out, int n) {
  __shared__ float As[64 * 68];
  __shared__ float Ws[64 * 128];
  int tid = threadIdx.x;
  int m0 = blockIdx.x * 64;
  int ty = tid >> 4, tx = tid & 15;
  float4 acc[4][2];
#pragma unroll
  for (int i = 0; i < 4; ++i) {
    acc[i][0] = make_float4(0.f, 0.f, 0.f, 0.f);
    acc[i][1] = make_float4(0.f, 0.f, 0.f, 0.f);
  }
  for (int kb = 0; kb < 8; ++kb) {
#pragma unroll
    for (int i = 0; i < 4; ++i) {
      int l = tid + i * 256;
      int row = l >> 4, c4 = l & 15;
      float4 v = make_float4(0.f, 0.f, 0.f, 0.f);
      if (m0 + row < n) v = *(const float4*)(agg + (size_t)(m0 + row) * 512 + kb * 64 + c4 * 4);
      *(float4*)(As + row * 68 + c4 * 4) = v;
    }
#pragma unroll
    for (int i = 0; i < 8; ++i) {
      int l = tid + i * 256;
      int k = l >> 5, c4 = l & 31;
      *(float4*)(Ws + k * 128 + c4 * 4) =
          *(const float4*)(woT + (size_t)(kb * 64 + k) * 128 + c4 * 4);
    }
    __syncthreads();
    for (int k = 0; k < 64; ++k) {
      float4 w0 = *(const float4*)(Ws + k * 128 + tx * 8);
      float4 w1 = *(const float4*)(Ws + k * 128 + tx * 8 + 4);
#pragma unroll
      for (int i = 0; i < 4; ++i) {
        float a = As[(ty * 4 + i) * 68 + k];
        acc[i][0] = fma4(a, w0, acc[i][0]);
        acc[i][1] = fma4(a, w1, acc[i][1]);
      }
    }
    __syncthreads();
  }
#pragma unroll
  for (int i = 0; i < 4; ++i) {
    int row = m0 + ty * 4 + i;
    if (row < n) {
      float* op = out + (size_t)row * 128 + tx * 8;
      float4 c0 = *(float4*)op;
      float4 c1 = *(float4*)(op + 4);
      c0.x += acc[i][0].x; c0.y += acc[i][0].y; c0.z += acc[i][0].z; c0.w += acc[i][0].w;
      c1.x += acc[i][1].x; c1.y += acc[i][1].y; c1.z += acc[i][1].z; c1.w += acc[i][1].w;
      *(float4*)op = c0;
      *(float4*)(op + 4) = c1;
    }
  }
}

// ---------- launch ----------
extern "C" void kernel_launch(void* const* d_in, const int* in_sizes, int n_in,
                              void* d_out, int out_size, void* d_ws, size_t ws_size,
                              hipStream_t stream) {
  const float* h   = (const float*)d_in[0];
  const float* x   = (const float*)d_in[1];
  const int*   ei  = (const int*)d_in[2];
  const int*   mask= (const int*)d_in[3];
  const float* wq  = (const float*)d_in[4];
  const float* bq  = (const float*)d_in[5];
  const float* wk  = (const float*)d_in[6];
  const float* bk  = (const float*)d_in[7];
  const float* wv  = (const float*)d_in[8];
  const float* bv  = (const float*)d_in[9];
  const float* wo  = (const float*)d_in[10];
  const float* bo  = (const float*)d_in[11];
  const float* pw1 = (const float*)d_in[12];
  const float* pb1 = (const float*)d_in[13];
  const float* pw2 = (const float*)d_in[14];
  const float* pb2 = (const float*)d_in[15];
  const float* ew1 = (const float*)d_in[16];
  const float* eb1 = (const float*)d_in[17];
  const float* ew2 = (const float*)d_in[18];
  const float* eb2 = (const float*)d_in[19];
  const float* eww = (const float*)d_in[20];
  const float* ewb = (const float*)d_in[21];
  const float* cw1 = (const float*)d_in[22];
  const float* cb1 = (const float*)d_in[23];
  const float* cw2 = (const float*)d_in[24];
  const float* cb2 = (const float*)d_in[25];
  const float* cw3 = (const float*)d_in[26];
  const float* cb3 = (const float*)d_in[27];

  int n = in_sizes[0] / 128;
  int E = in_sizes[3];

  char* wptr = (char*)d_ws;
  auto alloc = [&](size_t bytes) {
    char* p = wptr;
    wptr += (bytes + 255) & ~(size_t)255;
    return p;
  };
  ushort* qkv   = (ushort*)alloc((size_t)n * 1536 * 2);
  float* scores = (float*)alloc((size_t)E * 8 * 4);
  float* agg    = (float*)alloc((size_t)n * 512 * 4);
  float* wqkvT  = (float*)alloc((size_t)128 * 1536 * 4);
  float* ew1T   = (float*)alloc((size_t)264 * 256 * 4);
  float* ew2T   = (float*)alloc((size_t)256 * 256 * 4);
  float* pw1T   = (float*)alloc((size_t)6 * 256 * 4);
  float* woT    = (float*)alloc((size_t)512 * 128 * 4);
  float* cw1T   = (float*)alloc((size_t)3 * 256 * 4);
  float* cw2T   = (float*)alloc((size_t)256 * 256 * 4);
  float* cw3T   = (float*)alloc((size_t)256 * 128 * 4);
  int* offs     = (int*)alloc((size_t)(n + 1) * 4);
  int* cursor   = (int*)alloc((size_t)n * 4);
  int* eidl     = (int*)alloc((size_t)E * 4);

  hipMemsetAsync(cursor, 0, (size_t)n * 4, stream);

  transpose_pad<<<dim3((264 * 256 + 255) / 256), 256, 0, stream>>>(ew1, ew1T, 256, 263, 264);
  transpose_pad<<<dim3((256 * 256 + 255) / 256), 256, 0, stream>>>(ew2, ew2T, 256, 256, 256);
  transpose_pad<<<dim3((6 * 256 + 255) / 256),   256, 0, stream>>>(pw1, pw1T, 256, 6, 6);
  transpose_pad<<<dim3((512 * 128 + 255) / 256), 256, 0, stream>>>(wo, woT, 128, 512, 512);
  transpose_pad<<<dim3((3 * 256 + 255) / 256),   256, 0, stream>>>(cw1, cw1T, 256, 3, 3);
  transpose_pad<<<dim3((256 * 256 + 255) / 256), 256, 0, stream>>>(cw2, cw2T, 256, 256, 256);
  transpose_pad<<<dim3((256 * 128 + 255) / 256), 256, 0, stream>>>(cw3, cw3T, 128, 256, 256);
  build_wqkvT<<<dim3((128 * 1536 + 255) / 256), 256, 0, stream>>>(wq, wk, wv, wqkvT);

  qkv_kernel<<<dim3((n + 63) / 64, 24), 256, 0, stream>>>(h, wqkvT, bq, bk, bv, qkv, n);
  edge_mlp_kernel<<<dim3((E + TE - 1) / TE), 256, 0, stream>>>(
      h, x, ei, E, ew1T, eb1, ew2T, eb2, eww, ewb, pw1T, pb1, pw2, pb2, scores);
  count_kernel<<<dim3((E + 255) / 256), 256, 0, stream>>>(ei, cursor, E);
  scan_kernel<<<dim3(1), 1024, 0, stream>>>(cursor, offs, n);
  fill_kernel<<<dim3((E + 255) / 256), 256, 0, stream>>>(ei, cursor, eidl, E);
  qk_kernel<<<dim3((E * 8 + 255) / 256), 256, 0, stream>>>(ei, mask, qkv, scores, E);
  softmax_kernel<<<dim3(n), 64, 0, stream>>>(offs, eidl, scores, n);
  agg_kernel<<<dim3(n), 512, 0, stream>>>(offs, eidl, ei, scores, qkv, agg, n, E);
  coord_kernel<<<dim3((n + 7) / 8), 256, 0, stream>>>(x, cw1T, cb1, cw2T, cb2, cw3T, cb3,
                                                      bo, (float*)d_out, n);
  hipMemsetAsync((float*)d_out + (size_t)n * 128, 0, (size_t)n * 3 * 4, stream);
  out_gemm_kernel<<<dim3((n + 63) / 64), 256, 0, stream>>>(agg, woT, (float*)d_out, n);
}

// Round 2
// 1597.020 us; speedup vs baseline: 2.5131x; 2.5131x over previous
//
#include <hip/hip_runtime.h>

typedef unsigned int uint;
typedef unsigned short ushort;
typedef __attribute__((ext_vector_type(8))) short bf16x8;
typedef __attribute__((ext_vector_type(4))) float f32x4;

// ---------- helpers ----------
__device__ __forceinline__ float silu_f(float t) { return t / (1.f + expf(-t)); }
__device__ __forceinline__ float silu_fast(float t) { return t / (1.f + __expf(-t)); }

__device__ __forceinline__ float bf2f(ushort u) {
  union { uint i; float f; } v; v.i = ((uint)u) << 16; return v.f;
}
__device__ __forceinline__ ushort f2bf(float f) {
  union { float f; uint i; } v; v.f = f;
  uint r = (v.i + 0x7fffu + ((v.i >> 16) & 1u)) >> 16;
  return (ushort)r;
}
__device__ __forceinline__ float4 fma4(float a, float4 b, float4 c) {
  c.x = fmaf(a, b.x, c.x); c.y = fmaf(a, b.y, c.y);
  c.z = fmaf(a, b.z, c.z); c.w = fmaf(a, b.w, c.w);
  return c;
}

// ---------- weight prep ----------
// src [J][K] row-major -> dst [Kpad][J], rows k>=K zero
__global__ __launch_bounds__(256) void transpose_pad(const float* __restrict__ src,
                                                     float* __restrict__ dst,
                                                     int J, int K, int Kpad) {
  int idx = blockIdx.x * 256 + threadIdx.x;
  if (idx >= Kpad * J) return;
  int k = idx / J, j = idx % J;
  dst[idx] = (k < K) ? src[j * K + k] : 0.f;
}

__global__ __launch_bounds__(256) void build_wqkvT(const float* __restrict__ wq,
                                                   const float* __restrict__ wk,
                                                   const float* __restrict__ wv,
                                                   float* __restrict__ dst) {
  int idx = blockIdx.x * 256 + threadIdx.x;   // 128*1536
  if (idx >= 128 * 1536) return;
  int k = idx / 1536, j = idx % 1536;
  float v;
  if (j < 512)       v = wq[j * 128 + k];
  else if (j < 1024) v = wk[(j - 512) * 128 + k];
  else               v = wv[(j - 1024) * 128 + k];
  dst[idx] = v;
}

// W1big^T [512 n][288 k] bf16: n<256 -> ew1 row n; n>=256 -> pw1 at cols 257..262.
// Also b1big[512] = eb1 || pb1.
__global__ __launch_bounds__(256) void prep_w1t(const float* __restrict__ ew1,
                                                const float* __restrict__ eb1,
                                                const float* __restrict__ pw1,
                                                const float* __restrict__ pb1,
                                                short* __restrict__ W1T,
                                                float* __restrict__ b1big) {
  int idx = blockIdx.x * 256 + threadIdx.x;   // 512*288
  if (idx >= 512 * 288) return;
  int n = idx / 288, k = idx % 288;
  float v = 0.f;
  if (n < 256) { if (k < 263) v = ew1[n * 263 + k]; }
  else         { if (k >= 257 && k < 263) v = pw1[(n - 256) * 6 + (k - 257)]; }
  W1T[idx] = (short)f2bf(v);
  if (idx < 512) b1big[idx] = (idx < 256) ? eb1[idx] : pb1[idx - 256];
}

// W2big^T [16 h][512 k] bf16: h<8: k<256 -> (eww@ew2)[h][k], k>=256 -> pw2[h][k-256].
// biasC[h] = eb2@eww[h] + ewb[h] + pb2[h].
__global__ __launch_bounds__(256) void prep_w2t(const float* __restrict__ ew2,
                                                const float* __restrict__ eww,
                                                const float* __restrict__ eb2,
                                                const float* __restrict__ ewb,
                                                const float* __restrict__ pw2,
                                                const float* __restrict__ pb2,
                                                short* __restrict__ W2T,
                                                float* __restrict__ biasC) {
  int idx = blockIdx.x * 256 + threadIdx.x;   // 16*512
  if (idx >= 16 * 512) return;
  int hh = idx >> 9, k = idx & 511;
  float v = 0.f;
  if (hh < 8) {
    if (k < 256) {
      float s = 0.f;
      for (int j = 0; j < 256; ++j) s += eww[hh * 256 + j] * ew2[j * 256 + k];
      v = s;
    } else {
      v = pw2[hh * 256 + (k - 256)];
    }
  }
  W2T[idx] = (short)f2bf(v);
  if (idx < 16) {
    float b = 0.f;
    if (idx < 8) {
      float s = 0.f;
      for (int j = 0; j < 256; ++j) s += eww[idx * 256 + j] * eb2[j];
      b = s + ewb[idx] + pb2[idx];
    }
    biasC[idx] = b;
  }
}

// ---------- QKV GEMM: qkv[n][1536](bf16) = h[n][128] @ wqkvT + bias ----------
__global__ __launch_bounds__(256) void qkv_kernel(const float* __restrict__ h,
                                                  const float* __restrict__ wqkvT,
                                                  const float* __restrict__ bq,
                                                  const float* __restrict__ bk,
                                                  const float* __restrict__ bv,
                                                  ushort* __restrict__ qkv, int n) {
  __shared__ float As[64 * 68];
  __shared__ float Ws[64 * 64];
  int tid = threadIdx.x;
  int m0 = blockIdx.x * 64, jb = blockIdx.y * 64;
  int ty = tid >> 4, tx = tid & 15;
  float4 acc[4];
#pragma unroll
  for (int i = 0; i < 4; ++i) acc[i] = make_float4(0.f, 0.f, 0.f, 0.f);

  for (int kb = 0; kb < 2; ++kb) {
#pragma unroll
    for (int i = 0; i < 4; ++i) {
      int l = tid + i * 256;
      int row = l >> 4, c4 = l & 15;
      float4 v = make_float4(0.f, 0.f, 0.f, 0.f);
      if (m0 + row < n) v = *(const float4*)(h + (size_t)(m0 + row) * 128 + kb * 64 + c4 * 4);
      *(float4*)(As + row * 68 + c4 * 4) = v;
    }
#pragma unroll
    for (int i = 0; i < 4; ++i) {
      int l = tid + i * 256;
      int k = l >> 4, c4 = l & 15;
      *(float4*)(Ws + k * 64 + c4 * 4) =
          *(const float4*)(wqkvT + (size_t)(kb * 64 + k) * 1536 + jb + c4 * 4);
    }
    __syncthreads();
    for (int k = 0; k < 64; ++k) {
      float4 wv4 = *(const float4*)(Ws + k * 64 + tx * 4);
#pragma unroll
      for (int i = 0; i < 4; ++i) {
        float a = As[(ty * 4 + i) * 68 + k];
        acc[i] = fma4(a, wv4, acc[i]);
      }
    }
    __syncthreads();
  }
  int c = jb + tx * 4;
  float bb[4];
#pragma unroll
  for (int jj = 0; jj < 4; ++jj) {
    int col = c + jj;
    bb[jj] = (col < 512) ? bq[col] : (col < 1024) ? bk[col - 512] : bv[col - 1024];
  }
#pragma unroll
  for (int i = 0; i < 4; ++i) {
    int row = m0 + ty * 4 + i;
    if (row < n) {
      ushort4 st;
      st.x = f2bf(acc[i].x + bb[0]);
      st.y = f2bf(acc[i].y + bb[1]);
      st.z = f2bf(acc[i].z + bb[2]);
      st.w = f2bf(acc[i].w + bb[3]);
      *(ushort4*)(qkv + (size_t)row * 1536 + c) = st;
    }
  }
}

// ---------- fused edge MLP + pos-enc via MFMA ----------
// scores[e][8] = silu(A[e][264] @ W1big) @ W2big + biasC
// A cols: 0-127 h[row], 128-255 h[col], 256 rd, 257-259 xr, 260-262 xc, 263.. 0
#define EB 64       // edges per block
#define AS 296      // A_lds stride (bf16), >=288, mult of 8, 2-way banks
#define TS 72       // t1 chunk stride (bf16)

__global__ __launch_bounds__(256, 2) void edge_mfma_kernel(
    const float* __restrict__ h, const float* __restrict__ x,
    const int* __restrict__ ei, int E,
    const short* __restrict__ W1T, const float* __restrict__ b1big,
    const short* __restrict__ W2T, const float* __restrict__ biasC,
    float* __restrict__ scores)
{
  extern __shared__ char smem[];
  short* Albuf = (short*)smem;              // [EB][AS]  37.9 KB
  short* T1    = Albuf + EB * AS;           // [4][EB][TS] 36.9 KB
  float* slab  = (float*)smem;              // overlay: [4][EB][16] f32 = 16 KB

  int tid = threadIdx.x;
  int lane = tid & 63, w = tid >> 6;
  int l15 = lane & 15, l4 = lane >> 4;
  int eb0 = blockIdx.x * EB;

  // ---- gather: 4 threads per edge ----
  {
    int e = tid >> 2, p = tid & 3;
    int eg = eb0 + e; if (eg >= E) eg = E - 1;
    int r = ei[eg], c = ei[E + eg];
    const float* hr = h + (size_t)r * 128 + p * 32;
    const float* hc = h + (size_t)c * 128 + p * 32;
    short* arow = Albuf + e * AS;
#pragma unroll
    for (int i = 0; i < 4; ++i) {
      float4 a0 = *(const float4*)(hr + i * 8);
      float4 a1 = *(const float4*)(hr + i * 8 + 4);
      bf16x8 v;
      v[0] = (short)f2bf(a0.x); v[1] = (short)f2bf(a0.y);
      v[2] = (short)f2bf(a0.z); v[3] = (short)f2bf(a0.w);
      v[4] = (short)f2bf(a1.x); v[5] = (short)f2bf(a1.y);
      v[6] = (short)f2bf(a1.z); v[7] = (short)f2bf(a1.w);
      *(bf16x8*)(arow + p * 32 + i * 8) = v;
    }
#pragma unroll
    for (int i = 0; i < 4; ++i) {
      float4 a0 = *(const float4*)(hc + i * 8);
      float4 a1 = *(const float4*)(hc + i * 8 + 4);
      bf16x8 v;
      v[0] = (short)f2bf(a0.x); v[1] = (short)f2bf(a0.y);
      v[2] = (short)f2bf(a0.z); v[3] = (short)f2bf(a0.w);
      v[4] = (short)f2bf(a1.x); v[5] = (short)f2bf(a1.y);
      v[6] = (short)f2bf(a1.z); v[7] = (short)f2bf(a1.w);
      *(bf16x8*)(arow + 128 + p * 32 + i * 8) = v;
    }
    if (p == 0) {
      float xr0 = x[r*3], xr1 = x[r*3+1], xr2 = x[r*3+2];
      float xc0 = x[c*3], xc1 = x[c*3+1], xc2 = x[c*3+2];
      float d0 = xr0-xc0, d1 = xr1-xc1, d2 = xr2-xc2;
      bf16x8 g;
      g[0] = (short)f2bf(d0*d0 + d1*d1 + d2*d2);
      g[1] = (short)f2bf(xr0); g[2] = (short)f2bf(xr1); g[3] = (short)f2bf(xr2);
      g[4] = (short)f2bf(xc0); g[5] = (short)f2bf(xc1); g[6] = (short)f2bf(xc2);
      g[7] = 0;
      *(bf16x8*)(arow + 256) = g;
    } else {
      bf16x8 z = {0,0,0,0,0,0,0,0};
      *(bf16x8*)(arow + 256 + p * 8) = z;   // zero cols 264..287
    }
  }
  __syncthreads();

  f32x4 sacc[4];
#pragma unroll
  for (int ef = 0; ef < 4; ++ef) sacc[ef] = (f32x4){0.f, 0.f, 0.f, 0.f};

  short* t1w = T1 + w * (EB * TS);

  // each wave: 2 chunks of 64 n-cols; layer1 swapped (D^T[n][e]) then layer2 partial
  for (int cch = 0; cch < 2; ++cch) {
    int n0 = (w * 2 + cch) * 64;
    f32x4 acc[4][4];
#pragma unroll
    for (int mf = 0; mf < 4; ++mf)
#pragma unroll
      for (int ef = 0; ef < 4; ++ef) acc[mf][ef] = (f32x4){0.f, 0.f, 0.f, 0.f};

    for (int ks = 0; ks < 9; ++ks) {
      bf16x8 aW[4], bE[4];
#pragma unroll
      for (int mf = 0; mf < 4; ++mf)
        aW[mf] = *(const bf16x8*)(W1T + (size_t)(n0 + mf * 16 + l15) * 288 + ks * 32 + l4 * 8);
#pragma unroll
      for (int ef = 0; ef < 4; ++ef)
        bE[ef] = *(const bf16x8*)(Albuf + (ef * 16 + l15) * AS + ks * 32 + l4 * 8);
#pragma unroll
      for (int mf = 0; mf < 4; ++mf)
#pragma unroll
        for (int ef = 0; ef < 4; ++ef)
          acc[mf][ef] = __builtin_amdgcn_mfma_f32_16x16x32_bf16(aW[mf], bE[ef], acc[mf][ef], 0, 0, 0);
    }
    // bias + silu + packed store of t1 chunk (lane's 4 regs are n-contiguous)
#pragma unroll
    for (int mf = 0; mf < 4; ++mf) {
      int nl = mf * 16 + l4 * 4;           // chunk-local col base
      float4 bias = *(const float4*)(b1big + n0 + nl);
#pragma unroll
      for (int ef = 0; ef < 4; ++ef) {
        int e = ef * 16 + l15;
        f32x4 v = acc[mf][ef];
        float s0 = silu_fast(v[0] + bias.x);
        float s1 = silu_fast(v[1] + bias.y);
        float s2 = silu_fast(v[2] + bias.z);
        float s3 = silu_fast(v[3] + bias.w);
        uint2 pk;
        pk.x = (uint)f2bf(s0) | ((uint)f2bf(s1) << 16);
        pk.y = (uint)f2bf(s2) | ((uint)f2bf(s3) << 16);
        *(uint2*)(t1w + e * TS + nl) = pk;
      }
    }
    // layer2 partial over this 64-col chunk (same wave wrote t1w; compiler waits lgkm)
#pragma unroll
    for (int ks2 = 0; ks2 < 2; ++ks2) {
      bf16x8 bW2 = *(const bf16x8*)(W2T + (size_t)l15 * 512 + n0 + ks2 * 32 + l4 * 8);
#pragma unroll
      for (int ef = 0; ef < 4; ++ef) {
        bf16x8 aT = *(const bf16x8*)(t1w + (ef * 16 + l15) * TS + ks2 * 32 + l4 * 8);
        sacc[ef] = __builtin_amdgcn_mfma_f32_16x16x32_bf16(aT, bW2, sacc[ef], 0, 0, 0);
      }
    }
  }
  __syncthreads();   // all Albuf reads done; safe to overlay slab
#pragma unroll
  for (int ef = 0; ef < 4; ++ef)
#pragma unroll
    for (int i = 0; i < 4; ++i)
      slab[(w * EB + ef * 16 + l4 * 4 + i) * 16 + l15] = sacc[ef][i];
  __syncthreads();
  for (int t = tid; t < EB * 8; t += 256) {
    int e = t >> 3, hh = t & 7;
    float s = biasC[hh]
            + slab[(0 * EB + e) * 16 + hh] + slab[(1 * EB + e) * 16 + hh]
            + slab[(2 * EB + e) * 16 + hh] + slab[(3 * EB + e) * 16 + hh];
    if (eb0 + e < E) scores[(size_t)(eb0 + e) * 8 + hh] = s;
  }
}

// ---------- CSR build ----------
__global__ __launch_bounds__(256) void count_kernel(const int* __restrict__ ei,
                                                    int* __restrict__ cnt, int E) {
  int e = blockIdx.x * 256 + threadIdx.x;
  if (e < E) atomicAdd(&cnt[ei[e]], 1);
}

__global__ __launch_bounds__(1024) void scan_kernel(int* __restrict__ cnt,
                                                    int* __restrict__ offs, int n) {
  __shared__ int part[1024];
  int t = threadIdx.x;
  int chunk = (n + 1023) >> 10;
  int s = t * chunk, e = min(s + chunk, n);
  int sum = 0;
  for (int i = s; i < e; ++i) sum += cnt[i];
  part[t] = sum;
  __syncthreads();
  for (int off = 1; off < 1024; off <<= 1) {
    int v = (t >= off) ? part[t - off] : 0;
    __syncthreads();
    part[t] += v;
    __syncthreads();
  }
  int run = (t == 0) ? 0 : part[t - 1];
  for (int i = s; i < e; ++i) {
    int c = cnt[i];
    offs[i] = run;
    cnt[i] = run;     // becomes cursor
    run += c;
  }
  if (t == 1023) offs[n] = run;
}

__global__ __launch_bounds__(256) void fill_kernel(const int* __restrict__ ei,
                                                   int* __restrict__ cursor,
                                                   int* __restrict__ eidl, int E) {
  int e = blockIdx.x * 256 + threadIdx.x;
  if (e < E) {
    int p = atomicAdd(&cursor[ei[e]], 1);
    eidl[p] = e;
  }
}

// ---------- QK scores ----------
__device__ __forceinline__ float pairdot(uint a, uint b) {
  return bf2f((ushort)(a & 0xffffu)) * bf2f((ushort)(b & 0xffffu)) +
         bf2f((ushort)(a >> 16)) * bf2f((ushort)(b >> 16));
}

__global__ __launch_bounds__(256) void qk_kernel(const int* __restrict__ ei,
                                                 const int* __restrict__ mask,
                                                 const ushort* __restrict__ qkv,
                                                 float* __restrict__ scores, int E) {
  int idx = blockIdx.x * 256 + threadIdx.x;
  int e = idx >> 3, hh = idx & 7;
  if (e >= E) return;
  int r = ei[e], c = ei[E + e];
  const uint4* qp = (const uint4*)(qkv + (size_t)r * 1536 + hh * 64);
  const uint4* kp = (const uint4*)(qkv + (size_t)c * 1536 + 512 + hh * 64);
  float dot = 0.f;
#pragma unroll
  for (int i = 0; i < 8; ++i) {
    uint4 qa = qp[i];
    uint4 ka = kp[i];
    dot += pairdot(qa.x, ka.x) + pairdot(qa.y, ka.y) +
           pairdot(qa.z, ka.z) + pairdot(qa.w, ka.w);
  }
  float s = scores[idx];
  s = mask[e] ? (dot * 0.125f + s) : -1e9f;
  scores[idx] = s;
}

// ---------- per-node scatter softmax (in place on scores) ----------
__global__ __launch_bounds__(64) void softmax_kernel(const int* __restrict__ offs,
                                                     const int* __restrict__ eidl,
                                                     float* __restrict__ scores, int n) {
  int node = blockIdx.x;
  int start = offs[node], deg = offs[node + 1] - start;
  if (deg == 0) return;
  int l = threadIdx.x;
  int hh = l & 7, le = l >> 3;
  float m = -3.0e38f;
  for (int b = le; b < deg; b += 8) {
    int eid = eidl[start + b];
    m = fmaxf(m, scores[(size_t)eid * 8 + hh]);
  }
  m = fmaxf(m, __shfl_xor(m, 8));
  m = fmaxf(m, __shfl_xor(m, 16));
  m = fmaxf(m, __shfl_xor(m, 32));
  float ssum = 0.f;
  for (int b = le; b < deg; b += 8) {
    int eid = eidl[start + b];
    ssum += expf(scores[(size_t)eid * 8 + hh] - m);
  }
  ssum += __shfl_xor(ssum, 8);
  ssum += __shfl_xor(ssum, 16);
  ssum += __shfl_xor(ssum, 32);
  float inv = 1.f / (ssum + 1e-8f);
  for (int b = le; b < deg; b += 8) {
    int eid = eidl[start + b];
    size_t ix = (size_t)eid * 8 + hh;
    scores[ix] = expf(scores[ix] - m) * inv;
  }
}

// ---------- aggregation: agg[node][512] = sum attn * v[col] ----------
__global__ __launch_bounds__(512) void agg_kernel(const int* __restrict__ offs,
                                                  const int* __restrict__ eidl,
                                                  const int* __restrict__ ei,
                                                  const float* __restrict__ scores,
                                                  const ushort* __restrict__ qkv,
                                                  float* __restrict__ agg, int n, int E) {
  int node = blockIdx.x;
  int d = threadIdx.x;
  int start = offs[node], end = offs[node + 1];
  float acc = 0.f;
  for (int i = start; i < end; ++i) {
    int eid = eidl[i];
    int c = ei[E + eid];
    float a = scores[(size_t)eid * 8 + (d >> 6)];
    float v = bf2f(qkv[(size_t)c * 1536 + 1024 + d]);
    acc = fmaf(a, v, acc);
  }
  agg[(size_t)node * 512 + d] = acc;
}

// ---------- coord MLP (8 nodes/block), writes base (coord + bo) into d_out ----------
__global__ __launch_bounds__(256) void coord_kernel(
    const float* __restrict__ x,
    const float* __restrict__ cw1T, const float* __restrict__ cb1,
    const float* __restrict__ cw2T, const float* __restrict__ cb2,
    const float* __restrict__ cw3T, const float* __restrict__ cb3,
    const float* __restrict__ bo, float* __restrict__ out, int n) {
  __shared__ float c1[8 * 256];
  __shared__ float c2[8 * 256];
  int j = threadIdx.x;
  int n0 = blockIdx.x * 8;
  float w0 = cw1T[j], w1 = cw1T[256 + j], w2 = cw1T[512 + j], b1 = cb1[j];
#pragma unroll
  for (int nn = 0; nn < 8; ++nn) {
    int node = min(n0 + nn, n - 1);
    float t = fmaf(x[node * 3 + 2], w2,
              fmaf(x[node * 3 + 1], w1, fmaf(x[node * 3 + 0], w0, b1)));
    c1[nn * 256 + j] = silu_f(t);
  }
  __syncthreads();
  {
    float acc[8];
    float b2 = cb2[j];
#pragma unroll
    for (int nn = 0; nn < 8; ++nn) acc[nn] = b2;
    for (int k = 0; k < 256; ++k) {
      float wv = cw2T[k * 256 + j];
#pragma unroll
      for (int nn = 0; nn < 8; ++nn) acc[nn] = fmaf(c1[nn * 256 + k], wv, acc[nn]);
    }
#pragma unroll
    for (int nn = 0; nn < 8; ++nn) c2[nn * 256 + j] = silu_f(acc[nn]);
  }
  __syncthreads();
  if (j < 128) {
    float acc[8];
    float b3 = cb3[j] + bo[j];
#pragma unroll
    for (int nn = 0; nn < 8; ++nn) acc[nn] = b3;
    for (int k = 0; k < 256; ++k) {
      float wv = cw3T[k * 128 + j];
#pragma unroll
      for (int nn = 0; nn < 8; ++nn) acc[nn] = fmaf(c2[nn * 256 + k], wv, acc[nn]);
    }
#pragma unroll
    for (int nn = 0; nn < 8; ++nn) {
      int node = n0 + nn;
      if (node < n) out[(size_t)node * 128 + j] = acc[nn];
    }
  }
}

// ---------- out GEMM: out[n][128] += agg[n][512] @ woT ----------
__global__ __launch_bounds__(256) void out_gemm_kernel(const float* __restrict__ agg,
                                                       const float* __restrict__ woT,
                                                       float* __restrict__ out, int n) {
  __shared__ float As[64 * 68];
  __shared__ float Ws[64 * 128];
  int tid = threadIdx.x;
  int m0 = blockIdx.x * 64;
  int ty = tid >> 4, tx = tid & 15;
  float4 acc[4][2];
#pragma unroll
  for (int i = 0; i < 4; ++i) {
    acc[i][0] = make_float4(0.f, 0.f, 0.f, 0.f);
    acc[i][1] = make_float4(0.f, 0.f, 0.f, 0.f);
  }
  for (int kb = 0; kb < 8; ++kb) {
#pragma unroll
    for (int i = 0; i < 4; ++i) {
      int l = tid + i * 256;
      int row = l >> 4, c4 = l & 15;
      float4 v = make_float4(0.f, 0.f, 0.f, 0.f);
      if (m0 + row < n) v = *(const float4*)(agg + (size_t)(m0 + row) * 512 + kb * 64 + c4 * 4);
      *(float4*)(As + row * 68 + c4 * 4) = v;
    }
#pragma unroll
    for (int i = 0; i < 8; ++i) {
      int l = tid + i * 256;
      int k = l >> 5, c4 = l & 31;
      *(float4*)(Ws + k * 128 + c4 * 4) =
          *(const float4*)(woT + (size_t)(kb * 64 + k) * 128 + c4 * 4);
    }
    __syncthreads();
    for (int k = 0; k < 64; ++k) {
      float4 w0 = *(const float4*)(Ws + k * 128 + tx * 8);
      float4 w1 = *(const float4*)(Ws + k * 128 + tx * 8 + 4);
#pragma unroll
      for (int i = 0; i < 4; ++i) {
        float a = As[(ty * 4 + i) * 68 + k];
        acc[i][0] = fma4(a, w0, acc[i][0]);
        acc[i][1] = fma4(a, w1, acc[i][1]);
      }
    }
    __syncthreads();
  }
#pragma unroll
  for (int i = 0; i < 4; ++i) {
    int row = m0 + ty * 4 + i;
    if (row < n) {
      float* op = out + (size_t)row * 128 + tx * 8;
      float4 c0 = *(float4*)op;
      float4 c1 = *(float4*)(op + 4);
      c0.x += acc[i][0].x; c0.y += acc[i][0].y; c0.z += acc[i][0].z; c0.w += acc[i][0].w;
      c1.x += acc[i][1].x; c1.y += acc[i][1].y; c1.z += acc[i][1].z; c1.w += acc[i][1].w;
      *(float4*)op = c0;
      *(float4*)(op + 4) = c1;
    }
  }
}

// ---------- launch ----------
extern "C" void kernel_launch(void* const* d_in, const int* in_sizes, int n_in,
                              void* d_out, int out_size, void* d_ws, size_t ws_size,
                              hipStream_t stream) {
  const float* h   = (const float*)d_in[0];
  const float* x   = (const float*)d_in[1];
  const int*   ei  = (const int*)d_in[2];
  const int*   mask= (const int*)d_in[3];
  const float* wq  = (const float*)d_in[4];
  const float* bq  = (const float*)d_in[5];
  const float* wk  = (const float*)d_in[6];
  const float* bk  = (const float*)d_in[7];
  const float* wv  = (const float*)d_in[8];
  const float* bv  = (const float*)d_in[9];
  const float* wo  = (const float*)d_in[10];
  const float* bo  = (const float*)d_in[11];
  const float* pw1 = (const float*)d_in[12];
  const float* pb1 = (const float*)d_in[13];
  const float* pw2 = (const float*)d_in[14];
  const float* pb2 = (const float*)d_in[15];
  const float* ew1 = (const float*)d_in[16];
  const float* eb1 = (const float*)d_in[17];
  const float* ew2 = (const float*)d_in[18];
  const float* eb2 = (const float*)d_in[19];
  const float* eww = (const float*)d_in[20];
  const float* ewb = (const float*)d_in[21];
  const float* cw1 = (const float*)d_in[22];
  const float* cb1 = (const float*)d_in[23];
  const float* cw2 = (const float*)d_in[24];
  const float* cb2 = (const float*)d_in[25];
  const float* cw3 = (const float*)d_in[26];
  const float* cb3 = (const float*)d_in[27];

  int n = in_sizes[0] / 128;
  int E = in_sizes[3];

  char* wptr = (char*)d_ws;
  auto alloc = [&](size_t bytes) {
    char* p = wptr;
    wptr += (bytes + 255) & ~(size_t)255;
    return p;
  };
  ushort* qkv   = (ushort*)alloc((size_t)n * 1536 * 2);
  float* scores = (float*)alloc((size_t)E * 8 * 4);
  float* agg    = (float*)alloc((size_t)n * 512 * 4);
  float* wqkvT  = (float*)alloc((size_t)128 * 1536 * 4);
  short* W1T    = (short*)alloc((size_t)512 * 288 * 2);
  float* b1big  = (float*)alloc((size_t)512 * 4);
  short* W2T    = (short*)alloc((size_t)16 * 512 * 2);
  float* biasC  = (float*)alloc((size_t)16 * 4);
  float* woT    = (float*)alloc((size_t)512 * 128 * 4);
  float* cw1T   = (float*)alloc((size_t)3 * 256 * 4);
  float* cw2T   = (float*)alloc((size_t)256 * 256 * 4);
  float* cw3T   = (float*)alloc((size_t)256 * 128 * 4);
  int* offs     = (int*)alloc((size_t)(n + 1) * 4);
  int* cursor   = (int*)alloc((size_t)n * 4);
  int* eidl     = (int*)alloc((size_t)E * 4);

  hipMemsetAsync(cursor, 0, (size_t)n * 4, stream);

  transpose_pad<<<dim3((512 * 128 + 255) / 256), 256, 0, stream>>>(wo, woT, 128, 512, 512);
  transpose_pad<<<dim3((3 * 256 + 255) / 256),   256, 0, stream>>>(cw1, cw1T, 256, 3, 3);
  transpose_pad<<<dim3((256 * 256 + 255) / 256), 256, 0, stream>>>(cw2, cw2T, 256, 256, 256);
  transpose_pad<<<dim3((256 * 128 + 255) / 256), 256, 0, stream>>>(cw3, cw3T, 128, 256, 256);
  build_wqkvT<<<dim3((128 * 1536 + 255) / 256), 256, 0, stream>>>(wq, wk, wv, wqkvT);
  prep_w1t<<<dim3((512 * 288 + 255) / 256), 256, 0, stream>>>(ew1, eb1, pw1, pb1, W1T, b1big);
  prep_w2t<<<dim3((16 * 512 + 255) / 256), 256, 0, stream>>>(ew2, eww, eb2, ewb, pw2, pb2, W2T, biasC);

  qkv_kernel<<<dim3((n + 63) / 64, 24), 256, 0, stream>>>(h, wqkvT, bq, bk, bv, qkv, n);

  size_t edge_lds = (size_t)(EB * AS + 4 * EB * TS) * 2;   // 74752 B
  edge_mfma_kernel<<<dim3((E + EB - 1) / EB), 256, edge_lds, stream>>>(
      h, x, ei, E, W1T, b1big, W2T, biasC, scores);

  count_kernel<<<dim3((E + 255) / 256), 256, 0, stream>>>(ei, cursor, E);
  scan_kernel<<<dim3(1), 1024, 0, stream>>>(cursor, offs, n);
  fill_kernel<<<dim3((E + 255) / 256), 256, 0, stream>>>(ei, cursor, eidl, E);
  qk_kernel<<<dim3((E * 8 + 255) / 256), 256, 0, stream>>>(ei, mask, qkv, scores, E);
  softmax_kernel<<<dim3(n), 64, 0, stream>>>(offs, eidl, scores, n);
  agg_kernel<<<dim3(n), 512, 0, stream>>>(offs, eidl, ei, scores, qkv, agg, n, E);
  coord_kernel<<<dim3((n + 7) / 8), 256, 0, stream>>>(x, cw1T, cb1, cw2T, cb2, cw3T, cb3,
                                                      bo, (float*)d_out, n);
  hipMemsetAsync((float*)d_out + (size_t)n * 128, 0, (size_t)n * 3 * 4, stream);
  out_gemm_kernel<<<dim3((n + 63) / 64), 256, 0, stream>>>(agg, woT, (float*)d_out, n);
}

// Round 3
// 878.692 us; speedup vs baseline: 4.5676x; 1.8175x over previous
//
#include <hip/hip_runtime.h>

typedef unsigned int uint;
typedef unsigned short ushort;
typedef __attribute__((ext_vector_type(8))) short bf16x8;
typedef __attribute__((ext_vector_type(8))) ushort ushort8;
typedef __attribute__((ext_vector_type(4))) float f32x4;

// ---------- helpers ----------
__device__ __forceinline__ float silu_f(float t) { return t / (1.f + expf(-t)); }
__device__ __forceinline__ float silu_fast(float t) { return t / (1.f + __expf(-t)); }

__device__ __forceinline__ float bf2f(ushort u) {
  union { uint i; float f; } v; v.i = ((uint)u) << 16; return v.f;
}
__device__ __forceinline__ ushort f2bf(float f) {
  union { float f; uint i; } v; v.f = f;
  uint r = (v.i + 0x7fffu + ((v.i >> 16) & 1u)) >> 16;
  return (ushort)r;
}
__device__ __forceinline__ float4 fma4(float a, float4 b, float4 c) {
  c.x = fmaf(a, b.x, c.x); c.y = fmaf(a, b.y, c.y);
  c.z = fmaf(a, b.z, c.z); c.w = fmaf(a, b.w, c.w);
  return c;
}

// ---------- weight prep ----------
// src [J][K] row-major -> dst [Kpad][J], rows k>=K zero
__global__ __launch_bounds__(256) void transpose_pad(const float* __restrict__ src,
                                                     float* __restrict__ dst,
                                                     int J, int K, int Kpad) {
  int idx = blockIdx.x * 256 + threadIdx.x;
  if (idx >= Kpad * J) return;
  int k = idx / J, j = idx % J;
  dst[idx] = (k < K) ? src[j * K + k] : 0.f;
}

// h -> bf16
__global__ __launch_bounds__(256) void h2bf_kernel(const float* __restrict__ h,
                                                   ushort* __restrict__ h_bf, int total) {
  int idx = blockIdx.x * 256 + threadIdx.x;
  if (idx * 4 >= total) return;
  float4 v = *(const float4*)(h + idx * 4);
  ushort4 o;
  o.x = f2bf(v.x); o.y = f2bf(v.y); o.z = f2bf(v.z); o.w = f2bf(v.w);
  *(ushort4*)(h_bf + idx * 4) = o;
}

// wq||wk||wv as bf16 [1536 n][128 k] + bias concat
__global__ __launch_bounds__(256) void prep_wqkv(const float* __restrict__ wq,
                                                 const float* __restrict__ wk,
                                                 const float* __restrict__ wv,
                                                 const float* __restrict__ bq,
                                                 const float* __restrict__ bk,
                                                 const float* __restrict__ bv,
                                                 ushort* __restrict__ wqkv,
                                                 float* __restrict__ bqkv) {
  int idx = blockIdx.x * 256 + threadIdx.x;   // 1536*128
  if (idx >= 1536 * 128) return;
  int j = idx >> 7, k = idx & 127;
  float v = (j < 512) ? wq[j * 128 + k]
          : (j < 1024) ? wk[(j - 512) * 128 + k]
          : wv[(j - 1024) * 128 + k];
  wqkv[idx] = f2bf(v);
  if (idx < 1536)
    bqkv[idx] = (idx < 512) ? bq[idx] : (idx < 1024) ? bk[idx - 512] : bv[idx - 1024];
}

// W1big^T [512 n][288 k] bf16: n<256 -> ew1 row n; n>=256 -> pw1 at cols 257..262.
__global__ __launch_bounds__(256) void prep_w1t(const float* __restrict__ ew1,
                                                const float* __restrict__ eb1,
                                                const float* __restrict__ pw1,
                                                const float* __restrict__ pb1,
                                                short* __restrict__ W1T,
                                                float* __restrict__ b1big) {
  int idx = blockIdx.x * 256 + threadIdx.x;   // 512*288
  if (idx >= 512 * 288) return;
  int n = idx / 288, k = idx % 288;
  float v = 0.f;
  if (n < 256) { if (k < 263) v = ew1[n * 263 + k]; }
  else         { if (k >= 257 && k < 263) v = pw1[(n - 256) * 6 + (k - 257)]; }
  W1T[idx] = (short)f2bf(v);
  if (idx < 512) b1big[idx] = (idx < 256) ? eb1[idx] : pb1[idx - 256];
}

// W2big^T [16 h][512 k] bf16; biasC[h] = eb2@eww[h] + ewb[h] + pb2[h].
__global__ __launch_bounds__(256) void prep_w2t(const float* __restrict__ ew2,
                                                const float* __restrict__ eww,
                                                const float* __restrict__ eb2,
                                                const float* __restrict__ ewb,
                                                const float* __restrict__ pw2,
                                                const float* __restrict__ pb2,
                                                short* __restrict__ W2T,
                                                float* __restrict__ biasC) {
  int idx = blockIdx.x * 256 + threadIdx.x;   // 16*512
  if (idx >= 16 * 512) return;
  int hh = idx >> 9, k = idx & 511;
  float v = 0.f;
  if (hh < 8) {
    if (k < 256) {
      float s = 0.f;
      for (int j = 0; j < 256; ++j) s += eww[hh * 256 + j] * ew2[j * 256 + k];
      v = s;
    } else {
      v = pw2[hh * 256 + (k - 256)];
    }
  }
  W2T[idx] = (short)f2bf(v);
  if (idx < 16) {
    float b = 0.f;
    if (idx < 8) {
      float s = 0.f;
      for (int j = 0; j < 256; ++j) s += eww[idx * 256 + j] * eb2[j];
      b = s + ewb[idx] + pb2[idx];
    }
    biasC[idx] = b;
  }
}

// ---------- QKV via MFMA: [n][1536] = h_bf @ wqkv^T + bias, split to q/k/v tables ----------
__global__ __launch_bounds__(256) void qkv_mfma_kernel(
    const ushort* __restrict__ h_bf,    // [n][128]
    const ushort* __restrict__ wqkv,    // [1536][128]
    const float* __restrict__ bqkv,     // [1536]
    ushort* __restrict__ q_t, ushort* __restrict__ k_t, ushort* __restrict__ v_t,
    int n)
{
  __shared__ float oS[64 * 68];
  int tid = threadIdx.x;
  int lane = tid & 63, w = tid >> 6;
  int l15 = lane & 15, l4 = lane >> 4;
  int m0 = blockIdx.x * 64;
  int jb = blockIdx.y;                 // 0..23
  int n0 = jb * 64 + w * 16;

  f32x4 acc[4];
#pragma unroll
  for (int mf = 0; mf < 4; ++mf) acc[mf] = (f32x4){0.f, 0.f, 0.f, 0.f};

#pragma unroll
  for (int ks = 0; ks < 4; ++ks) {
    bf16x8 bW = *(const bf16x8*)(wqkv + (size_t)(n0 + l15) * 128 + ks * 32 + l4 * 8);
#pragma unroll
    for (int mf = 0; mf < 4; ++mf) {
      int gr = m0 + mf * 16 + l15; if (gr >= n) gr = n - 1;
      bf16x8 aH = *(const bf16x8*)(h_bf + (size_t)gr * 128 + ks * 32 + l4 * 8);
      acc[mf] = __builtin_amdgcn_mfma_f32_16x16x32_bf16(aH, bW, acc[mf], 0, 0, 0);
    }
  }
  // stage to LDS: oS[row][w*16 + l15]
#pragma unroll
  for (int mf = 0; mf < 4; ++mf)
#pragma unroll
    for (int i = 0; i < 4; ++i)
      oS[(mf * 16 + l4 * 4 + i) * 68 + w * 16 + l15] = acc[mf][i];
  __syncthreads();
  // write out: thread t -> row t>>2, 16 cols at (t&3)*16
  {
    int row = tid >> 2, cs = (tid & 3) * 16;
    int gr = m0 + row;
    if (gr < n) {
      int gc = jb * 64 + cs;
      int tbl = gc >> 9, cc = gc & 511;
      ushort* base = (tbl == 0) ? q_t : (tbl == 1) ? k_t : v_t;
      ushort8 o0, o1;
#pragma unroll
      for (int j = 0; j < 8; ++j) o0[j] = f2bf(oS[row * 68 + cs + j] + bqkv[gc + j]);
#pragma unroll
      for (int j = 0; j < 8; ++j) o1[j] = f2bf(oS[row * 68 + cs + 8 + j] + bqkv[gc + 8 + j]);
      *(ushort8*)(base + (size_t)gr * 512 + cc) = o0;
      *(ushort8*)(base + (size_t)gr * 512 + cc + 8) = o1;
    }
  }
}

// ---------- fused edge MLP + pos-enc via MFMA ----------
// scores[e][8] = silu(A[e][264] @ W1big) @ W2big + biasC
#define EB 64       // edges per block
#define AS 296      // A_lds stride (bf16)
#define TS 72       // t1 chunk stride (bf16)

__global__ __launch_bounds__(256, 2) void edge_mfma_kernel(
    const ushort* __restrict__ h_bf, const float* __restrict__ x,
    const int* __restrict__ ei, int E,
    const short* __restrict__ W1T, const float* __restrict__ b1big,
    const short* __restrict__ W2T, const float* __restrict__ biasC,
    float* __restrict__ scores)
{
  extern __shared__ char smem[];
  short* Albuf = (short*)smem;              // [EB][AS]
  short* T1    = Albuf + EB * AS;           // [4][EB][TS]
  float* slab  = (float*)smem;              // overlay: [4][EB][16] f32

  int tid = threadIdx.x;
  int lane = tid & 63, w = tid >> 6;
  int l15 = lane & 15, l4 = lane >> 4;
  int eb0 = blockIdx.x * EB;

  // ---- gather: 4 threads per edge (bf16 h rows, direct copy) ----
  {
    int e = tid >> 2, p = tid & 3;
    int eg = eb0 + e; if (eg >= E) eg = E - 1;
    int r = ei[eg], c = ei[E + eg];
    const ushort* hr = h_bf + (size_t)r * 128 + p * 32;
    const ushort* hc = h_bf + (size_t)c * 128 + p * 32;
    short* arow = Albuf + e * AS;
#pragma unroll
    for (int i = 0; i < 4; ++i)
      *(uint4*)(arow + p * 32 + i * 8) = *(const uint4*)(hr + i * 8);
#pragma unroll
    for (int i = 0; i < 4; ++i)
      *(uint4*)(arow + 128 + p * 32 + i * 8) = *(const uint4*)(hc + i * 8);
    if (p == 0) {
      float xr0 = x[r*3], xr1 = x[r*3+1], xr2 = x[r*3+2];
      float xc0 = x[c*3], xc1 = x[c*3+1], xc2 = x[c*3+2];
      float d0 = xr0-xc0, d1 = xr1-xc1, d2 = xr2-xc2;
      bf16x8 g;
      g[0] = (short)f2bf(d0*d0 + d1*d1 + d2*d2);
      g[1] = (short)f2bf(xr0); g[2] = (short)f2bf(xr1); g[3] = (short)f2bf(xr2);
      g[4] = (short)f2bf(xc0); g[5] = (short)f2bf(xc1); g[6] = (short)f2bf(xc2);
      g[7] = 0;
      *(bf16x8*)(arow + 256) = g;
    } else {
      bf16x8 z = {0,0,0,0,0,0,0,0};
      *(bf16x8*)(arow + 256 + p * 8) = z;
    }
  }
  __syncthreads();

  f32x4 sacc[4];
#pragma unroll
  for (int ef = 0; ef < 4; ++ef) sacc[ef] = (f32x4){0.f, 0.f, 0.f, 0.f};

  short* t1w = T1 + w * (EB * TS);

  for (int cch = 0; cch < 2; ++cch) {
    int n0 = (w * 2 + cch) * 64;
    f32x4 acc[4][4];
#pragma unroll
    for (int mf = 0; mf < 4; ++mf)
#pragma unroll
      for (int ef = 0; ef < 4; ++ef) acc[mf][ef] = (f32x4){0.f, 0.f, 0.f, 0.f};

    for (int ks = 0; ks < 9; ++ks) {
      bf16x8 aW[4], bE[4];
#pragma unroll
      for (int mf = 0; mf < 4; ++mf)
        aW[mf] = *(const bf16x8*)(W1T + (size_t)(n0 + mf * 16 + l15) * 288 + ks * 32 + l4 * 8);
#pragma unroll
      for (int ef = 0; ef < 4; ++ef)
        bE[ef] = *(const bf16x8*)(Albuf + (ef * 16 + l15) * AS + ks * 32 + l4 * 8);
#pragma unroll
      for (int mf = 0; mf < 4; ++mf)
#pragma unroll
        for (int ef = 0; ef < 4; ++ef)
          acc[mf][ef] = __builtin_amdgcn_mfma_f32_16x16x32_bf16(aW[mf], bE[ef], acc[mf][ef], 0, 0, 0);
    }
#pragma unroll
    for (int mf = 0; mf < 4; ++mf) {
      int nl = mf * 16 + l4 * 4;
      float4 bias = *(const float4*)(b1big + n0 + nl);
#pragma unroll
      for (int ef = 0; ef < 4; ++ef) {
        int e = ef * 16 + l15;
        f32x4 v = acc[mf][ef];
        float s0 = silu_fast(v[0] + bias.x);
        float s1 = silu_fast(v[1] + bias.y);
        float s2 = silu_fast(v[2] + bias.z);
        float s3 = silu_fast(v[3] + bias.w);
        uint2 pk;
        pk.x = (uint)f2bf(s0) | ((uint)f2bf(s1) << 16);
        pk.y = (uint)f2bf(s2) | ((uint)f2bf(s3) << 16);
        *(uint2*)(t1w + e * TS + nl) = pk;
      }
    }
#pragma unroll
    for (int ks2 = 0; ks2 < 2; ++ks2) {
      bf16x8 bW2 = *(const bf16x8*)(W2T + (size_t)l15 * 512 + n0 + ks2 * 32 + l4 * 8);
#pragma unroll
      for (int ef = 0; ef < 4; ++ef) {
        bf16x8 aT = *(const bf16x8*)(t1w + (ef * 16 + l15) * TS + ks2 * 32 + l4 * 8);
        sacc[ef] = __builtin_amdgcn_mfma_f32_16x16x32_bf16(aT, bW2, sacc[ef], 0, 0, 0);
      }
    }
  }
  __syncthreads();
#pragma unroll
  for (int ef = 0; ef < 4; ++ef)
#pragma unroll
    for (int i = 0; i < 4; ++i)
      slab[(w * EB + ef * 16 + l4 * 4 + i) * 16 + l15] = sacc[ef][i];
  __syncthreads();
  for (int t = tid; t < EB * 8; t += 256) {
    int e = t >> 3, hh = t & 7;
    float s = biasC[hh]
            + slab[(0 * EB + e) * 16 + hh] + slab[(1 * EB + e) * 16 + hh]
            + slab[(2 * EB + e) * 16 + hh] + slab[(3 * EB + e) * 16 + hh];
    if (eb0 + e < E) scores[(size_t)(eb0 + e) * 8 + hh] = s;
  }
}

// ---------- CSR build ----------
__global__ __launch_bounds__(256) void count_kernel(const int* __restrict__ ei,
                                                    int* __restrict__ cnt, int E) {
  int e = blockIdx.x * 256 + threadIdx.x;
  if (e < E) atomicAdd(&cnt[ei[e]], 1);
}

__global__ __launch_bounds__(1024) void scan_kernel(int* __restrict__ cnt,
                                                    int* __restrict__ offs, int n) {
  __shared__ int part[1024];
  int t = threadIdx.x;
  int chunk = (n + 1023) >> 10;
  int s = t * chunk, e = min(s + chunk, n);
  int sum = 0;
  for (int i = s; i < e; ++i) sum += cnt[i];
  part[t] = sum;
  __syncthreads();
  for (int off = 1; off < 1024; off <<= 1) {
    int v = (t >= off) ? part[t - off] : 0;
    __syncthreads();
    part[t] += v;
    __syncthreads();
  }
  int run = (t == 0) ? 0 : part[t - 1];
  for (int i = s; i < e; ++i) {
    int c = cnt[i];
    offs[i] = run;
    cnt[i] = run;     // becomes cursor
    run += c;
  }
  if (t == 1023) offs[n] = run;
}

__global__ __launch_bounds__(256) void fill_kernel(const int* __restrict__ ei,
                                                   int* __restrict__ cursor,
                                                   int2* __restrict__ pairs, int E) {
  int e = blockIdx.x * 256 + threadIdx.x;
  if (e < E) {
    int p = atomicAdd(&cursor[ei[e]], 1);
    pairs[p] = make_int2(e, ei[E + e]);
  }
}

// ---------- fused QK + softmax + aggregation (flash-style CSR, 1 wave/node) ----------
__global__ __launch_bounds__(256) void attn_fused_kernel(
    const int* __restrict__ offs,
    const int2* __restrict__ pairs,
    const int* __restrict__ mask,
    const float* __restrict__ scores,     // mlp+pos scores [E][8]
    const ushort* __restrict__ q_t,
    const ushort* __restrict__ k_t,
    const ushort* __restrict__ v_t,
    float* __restrict__ agg, int n)
{
  int node = blockIdx.x * 4 + (threadIdx.x >> 6);
  if (node >= n) return;
  int lane = threadIdx.x & 63;          // head = lane>>3, dims (lane&7)*8..+8
  int start = offs[node], end = offs[node + 1];

  bf16x8 qv = *(const bf16x8*)(q_t + (size_t)node * 512 + lane * 8);
  float qf[8];
#pragma unroll
  for (int j = 0; j < 8; ++j) qf[j] = bf2f((ushort)qv[j]);

  float m = -3.0e38f, ssum = 0.f;
  float acc[8];
#pragma unroll
  for (int j = 0; j < 8; ++j) acc[j] = 0.f;

  for (int i = start; i < end; ++i) {
    int2 pr = pairs[i];
    int eid = pr.x, col = pr.y;
    bf16x8 kv = *(const bf16x8*)(k_t + (size_t)col * 512 + lane * 8);
    bf16x8 vv = *(const bf16x8*)(v_t + (size_t)col * 512 + lane * 8);
    float dot = 0.f;
#pragma unroll
    for (int j = 0; j < 8; ++j) dot = fmaf(qf[j], bf2f((ushort)kv[j]), dot);
    dot += __shfl_xor(dot, 1);
    dot += __shfl_xor(dot, 2);
    dot += __shfl_xor(dot, 4);
    float sml = scores[(size_t)eid * 8 + (lane >> 3)];
    float s = mask[eid] ? fmaf(dot, 0.125f, sml) : -1e9f;
    if (s > m) {
      float scale = __expf(m - s);      // first edge: exp(-inf) = 0
      ssum *= scale;
#pragma unroll
      for (int j = 0; j < 8; ++j) acc[j] *= scale;
      m = s;
    }
    float e = __expf(s - m);
    ssum += e;
#pragma unroll
    for (int j = 0; j < 8; ++j) acc[j] = fmaf(e, bf2f((ushort)vv[j]), acc[j]);
  }
  float inv = 1.f / (ssum + 1e-8f);
  float4 o0, o1;
  o0.x = acc[0] * inv; o0.y = acc[1] * inv; o0.z = acc[2] * inv; o0.w = acc[3] * inv;
  o1.x = acc[4] * inv; o1.y = acc[5] * inv; o1.z = acc[6] * inv; o1.w = acc[7] * inv;
  float* op = agg + (size_t)node * 512 + lane * 8;
  *(float4*)op = o0;
  *(float4*)(op + 4) = o1;
}

// ---------- coord MLP (8 nodes/block), writes base (coord + bo) into d_out ----------
__global__ __launch_bounds__(256) void coord_kernel(
    const float* __restrict__ x,
    const float* __restrict__ cw1T, const float* __restrict__ cb1,
    const float* __restrict__ cw2T, const float* __restrict__ cb2,
    const float* __restrict__ cw3T, const float* __restrict__ cb3,
    const float* __restrict__ bo, float* __restrict__ out, int n) {
  __shared__ float c1[8 * 256];
  __shared__ float c2[8 * 256];
  int j = threadIdx.x;
  int n0 = blockIdx.x * 8;
  float w0 = cw1T[j], w1 = cw1T[256 + j], w2 = cw1T[512 + j], b1 = cb1[j];
#pragma unroll
  for (int nn = 0; nn < 8; ++nn) {
    int node = min(n0 + nn, n - 1);
    float t = fmaf(x[node * 3 + 2], w2,
              fmaf(x[node * 3 + 1], w1, fmaf(x[node * 3 + 0], w0, b1)));
    c1[nn * 256 + j] = silu_f(t);
  }
  __syncthreads();
  {
    float acc[8];
    float b2 = cb2[j];
#pragma unroll
    for (int nn = 0; nn < 8; ++nn) acc[nn] = b2;
    for (int k = 0; k < 256; ++k) {
      float wv = cw2T[k * 256 + j];
#pragma unroll
      for (int nn = 0; nn < 8; ++nn) acc[nn] = fmaf(c1[nn * 256 + k], wv, acc[nn]);
    }
#pragma unroll
    for (int nn = 0; nn < 8; ++nn) c2[nn * 256 + j] = silu_f(acc[nn]);
  }
  __syncthreads();
  if (j < 128) {
    float acc[8];
    float b3 = cb3[j] + bo[j];
#pragma unroll
    for (int nn = 0; nn < 8; ++nn) acc[nn] = b3;
    for (int k = 0; k < 256; ++k) {
      float wv = cw3T[k * 128 + j];
#pragma unroll
      for (int nn = 0; nn < 8; ++nn) acc[nn] = fmaf(c2[nn * 256 + k], wv, acc[nn]);
    }
#pragma unroll
    for (int nn = 0; nn < 8; ++nn) {
      int node = n0 + nn;
      if (node < n) out[(size_t)node * 128 + j] = acc[nn];
    }
  }
}

// ---------- out GEMM: out[n][128] += agg[n][512] @ woT ----------
__global__ __launch_bounds__(256) void out_gemm_kernel(const float* __restrict__ agg,
                                                       const float* __restrict__ woT,
                                                       float* __restrict__ out, int n) {
  __shared__ float As[64 * 68];
  __shared__ float Ws[64 * 128];
  int tid = threadIdx.x;
  int m0 = blockIdx.x * 64;
  int ty = tid >> 4, tx = tid & 15;
  float4 acc[4][2];
#pragma unroll
  for (int i = 0; i < 4; ++i) {
    acc[i][0] = make_float4(0.f, 0.f, 0.f, 0.f);
    acc[i][1] = make_float4(0.f, 0.f, 0.f, 0.f);
  }
  for (int kb = 0; kb < 8; ++kb) {
#pragma unroll
    for (int i = 0; i < 4; ++i) {
      int l = tid + i * 256;
      int row = l >> 4, c4 = l & 15;
      float4 v = make_float4(0.f, 0.f, 0.f, 0.f);
      if (m0 + row < n) v = *(const float4*)(agg + (size_t)(m0 + row) * 512 + kb * 64 + c4 * 4);
      *(float4*)(As + row * 68 + c4 * 4) = v;
    }
#pragma unroll
    for (int i = 0; i < 8; ++i) {
      int l = tid + i * 256;
      int k = l >> 5, c4 = l & 31;
      *(float4*)(Ws + k * 128 + c4 * 4) =
          *(const float4*)(woT + (size_t)(kb * 64 + k) * 128 + c4 * 4);
    }
    __syncthreads();
    for (int k = 0; k < 64; ++k) {
      float4 w0 = *(const float4*)(Ws + k * 128 + tx * 8);
      float4 w1 = *(const float4*)(Ws + k * 128 + tx * 8 + 4);
#pragma unroll
      for (int i = 0; i < 4; ++i) {
        float a = As[(ty * 4 + i) * 68 + k];
        acc[i][0] = fma4(a, w0, acc[i][0]);
        acc[i][1] = fma4(a, w1, acc[i][1]);
      }
    }
    __syncthreads();
  }
#pragma unroll
  for (int i = 0; i < 4; ++i) {
    int row = m0 + ty * 4 + i;
    if (row < n) {
      float* op = out + (size_t)row * 128 + tx * 8;
      float4 c0 = *(float4*)op;
      float4 c1 = *(float4*)(op + 4);
      c0.x += acc[i][0].x; c0.y += acc[i][0].y; c0.z += acc[i][0].z; c0.w += acc[i][0].w;
      c1.x += acc[i][1].x; c1.y += acc[i][1].y; c1.z += acc[i][1].z; c1.w += acc[i][1].w;
      *(float4*)op = c0;
      *(float4*)(op + 4) = c1;
    }
  }
}

// ---------- launch ----------
extern "C" void kernel_launch(void* const* d_in, const int* in_sizes, int n_in,
                              void* d_out, int out_size, void* d_ws, size_t ws_size,
                              hipStream_t stream) {
  const float* h   = (const float*)d_in[0];
  const float* x   = (const float*)d_in[1];
  const int*   ei  = (const int*)d_in[2];
  const int*   mask= (const int*)d_in[3];
  const float* wq  = (const float*)d_in[4];
  const float* bq  = (const float*)d_in[5];
  const float* wk  = (const float*)d_in[6];
  const float* bk  = (const float*)d_in[7];
  const float* wv  = (const float*)d_in[8];
  const float* bv  = (const float*)d_in[9];
  const float* wo  = (const float*)d_in[10];
  const float* bo  = (const float*)d_in[11];
  const float* pw1 = (const float*)d_in[12];
  const float* pb1 = (const float*)d_in[13];
  const float* pw2 = (const float*)d_in[14];
  const float* pb2 = (const float*)d_in[15];
  const float* ew1 = (const float*)d_in[16];
  const float* eb1 = (const float*)d_in[17];
  const float* ew2 = (const float*)d_in[18];
  const float* eb2 = (const float*)d_in[19];
  const float* eww = (const float*)d_in[20];
  const float* ewb = (const float*)d_in[21];
  const float* cw1 = (const float*)d_in[22];
  const float* cb1 = (const float*)d_in[23];
  const float* cw2 = (const float*)d_in[24];
  const float* cb2 = (const float*)d_in[25];
  const float* cw3 = (const float*)d_in[26];
  const float* cb3 = (const float*)d_in[27];

  int n = in_sizes[0] / 128;
  int E = in_sizes[3];

  char* wptr = (char*)d_ws;
  auto alloc = [&](size_t bytes) {
    char* p = wptr;
    wptr += (bytes + 255) & ~(size_t)255;
    return p;
  };
  ushort* q_t   = (ushort*)alloc((size_t)n * 512 * 2);
  ushort* k_t   = (ushort*)alloc((size_t)n * 512 * 2);
  ushort* v_t   = (ushort*)alloc((size_t)n * 512 * 2);
  ushort* h_bf  = (ushort*)alloc((size_t)n * 128 * 2);
  float* scores = (float*)alloc((size_t)E * 8 * 4);
  float* agg    = (float*)alloc((size_t)n * 512 * 4);
  ushort* wqkv  = (ushort*)alloc((size_t)1536 * 128 * 2);
  float* bqkv   = (float*)alloc((size_t)1536 * 4);
  short* W1T    = (short*)alloc((size_t)512 * 288 * 2);
  float* b1big  = (float*)alloc((size_t)512 * 4);
  short* W2T    = (short*)alloc((size_t)16 * 512 * 2);
  float* biasC  = (float*)alloc((size_t)16 * 4);
  float* woT    = (float*)alloc((size_t)512 * 128 * 4);
  float* cw1T   = (float*)alloc((size_t)3 * 256 * 4);
  float* cw2T   = (float*)alloc((size_t)256 * 256 * 4);
  float* cw3T   = (float*)alloc((size_t)256 * 128 * 4);
  int* offs     = (int*)alloc((size_t)(n + 1) * 4);
  int* cursor   = (int*)alloc((size_t)n * 4);
  int2* pairs   = (int2*)alloc((size_t)E * 8);

  hipMemsetAsync(cursor, 0, (size_t)n * 4, stream);

  transpose_pad<<<dim3((512 * 128 + 255) / 256), 256, 0, stream>>>(wo, woT, 128, 512, 512);
  transpose_pad<<<dim3((3 * 256 + 255) / 256),   256, 0, stream>>>(cw1, cw1T, 256, 3, 3);
  transpose_pad<<<dim3((256 * 256 + 255) / 256), 256, 0, stream>>>(cw2, cw2T, 256, 256, 256);
  transpose_pad<<<dim3((256 * 128 + 255) / 256), 256, 0, stream>>>(cw3, cw3T, 128, 256, 256);
  h2bf_kernel<<<dim3((n * 128 / 4 + 255) / 256), 256, 0, stream>>>(h, h_bf, n * 128);
  prep_wqkv<<<dim3((1536 * 128 + 255) / 256), 256, 0, stream>>>(wq, wk, wv, bq, bk, bv, wqkv, bqkv);
  prep_w1t<<<dim3((512 * 288 + 255) / 256), 256, 0, stream>>>(ew1, eb1, pw1, pb1, W1T, b1big);
  prep_w2t<<<dim3((16 * 512 + 255) / 256), 256, 0, stream>>>(ew2, eww, eb2, ewb, pw2, pb2, W2T, biasC);

  qkv_mfma_kernel<<<dim3((n + 63) / 64, 24), 256, 0, stream>>>(h_bf, wqkv, bqkv, q_t, k_t, v_t, n);

  size_t edge_lds = (size_t)(EB * AS + 4 * EB * TS) * 2;   // 74752 B
  edge_mfma_kernel<<<dim3((E + EB - 1) / EB), 256, edge_lds, stream>>>(
      h_bf, x, ei, E, W1T, b1big, W2T, biasC, scores);

  count_kernel<<<dim3((E + 255) / 256), 256, 0, stream>>>(ei, cursor, E);
  scan_kernel<<<dim3(1), 1024, 0, stream>>>(cursor, offs, n);
  fill_kernel<<<dim3((E + 255) / 256), 256, 0, stream>>>(ei, cursor, pairs, E);

  attn_fused_kernel<<<dim3((n + 3) / 4), 256, 0, stream>>>(
      offs, pairs, mask, scores, q_t, k_t, v_t, agg, n);

  coord_kernel<<<dim3((n + 7) / 8), 256, 0, stream>>>(x, cw1T, cb1, cw2T, cb2, cw3T, cb3,
                                                      bo, (float*)d_out, n);
  hipMemsetAsync((float*)d_out + (size_t)n * 128, 0, (size_t)n * 3 * 4, stream);
  out_gemm_kernel<<<dim3((n + 63) / 64), 256, 0, stream>>>(agg, woT, (float*)d_out, n);
}

// Round 4
// 710.972 us; speedup vs baseline: 5.6451x; 1.2359x over previous
//
#include <hip/hip_runtime.h>

typedef unsigned int uint;
typedef unsigned short ushort;
typedef unsigned char uchar;
typedef __attribute__((ext_vector_type(8))) short bf16x8;
typedef __attribute__((ext_vector_type(8))) ushort ushort8;
typedef __attribute__((ext_vector_type(4))) float f32x4;

// ---------- helpers ----------
__device__ __forceinline__ float silu_f(float t) { return t / (1.f + expf(-t)); }
__device__ __forceinline__ float silu_fast(float t) { return t / (1.f + __expf(-t)); }

__device__ __forceinline__ float bf2f(ushort u) {
  union { uint i; float f; } v; v.i = ((uint)u) << 16; return v.f;
}
__device__ __forceinline__ ushort f2bf(float f) {
  union { float f; uint i; } v; v.f = f;
  uint r = (v.i + 0x7fffu + ((v.i >> 16) & 1u)) >> 16;
  return (ushort)r;
}
// fp8 e4m3 (OCP) encode, RNE, sat-to-448 (values here are ~0.2 scale)
__device__ __forceinline__ uchar f2e4m3(float f) {
  uint u = __float_as_uint(f);
  uint s = (u >> 24) & 0x80u;
  uint m = u & 0x7fffffffu;
  if (m >= 0x43f00000u) return (uchar)(s | 0x7e);        // >=480 -> 448
  if (m >= 0x3c800000u) {                                // >= 2^-6 : normal
    uint r = m + 0x7ffffu + ((m >> 20) & 1u);
    uint e = (r >> 23) - 120u;
    if (e > 15u) return (uchar)(s | 0x7e);
    return (uchar)(s | (e << 3) | ((r >> 20) & 7u));
  }
  float az = __uint_as_float(m);                          // denormal: round(v*512)
  uint k = (uint)__float2int_rn(az * 512.f);
  return (uchar)(s | k);
}
__device__ __forceinline__ float e4m3f(uint b) {
  uint u = ((b & 0x80u) << 24) | ((b & 0x7fu) << 20);
  return __uint_as_float(u) * 0x1p+120f;
}

// ---------- weight prep ----------
__global__ __launch_bounds__(256) void h2bf_kernel(const float* __restrict__ h,
                                                   ushort* __restrict__ h_bf, int total) {
  int idx = blockIdx.x * 256 + threadIdx.x;
  if (idx * 4 >= total) return;
  float4 v = *(const float4*)(h + idx * 4);
  ushort4 o;
  o.x = f2bf(v.x); o.y = f2bf(v.y); o.z = f2bf(v.z); o.w = f2bf(v.w);
  *(ushort4*)(h_bf + idx * 4) = o;
}

__global__ __launch_bounds__(256) void prep_wqkv(const float* __restrict__ wq,
                                                 const float* __restrict__ wk,
                                                 const float* __restrict__ wv,
                                                 const float* __restrict__ bq,
                                                 const float* __restrict__ bk,
                                                 const float* __restrict__ bv,
                                                 ushort* __restrict__ wqkv,
                                                 float* __restrict__ bqkv) {
  int idx = blockIdx.x * 256 + threadIdx.x;   // 1536*128
  if (idx >= 1536 * 128) return;
  int j = idx >> 7, k = idx & 127;
  float v = (j < 512) ? wq[j * 128 + k]
          : (j < 1024) ? wk[(j - 512) * 128 + k]
          : wv[(j - 1024) * 128 + k];
  wqkv[idx] = f2bf(v);
  if (idx < 1536)
    bqkv[idx] = (idx < 512) ? bq[idx] : (idx < 1024) ? bk[idx - 512] : bv[idx - 1024];
}

__global__ __launch_bounds__(256) void prep_w1t(const float* __restrict__ ew1,
                                                const float* __restrict__ eb1,
                                                const float* __restrict__ pw1,
                                                const float* __restrict__ pb1,
                                                short* __restrict__ W1T,
                                                float* __restrict__ b1big) {
  int idx = blockIdx.x * 256 + threadIdx.x;   // 512*288
  if (idx >= 512 * 288) return;
  int n = idx / 288, k = idx % 288;
  float v = 0.f;
  if (n < 256) { if (k < 263) v = ew1[n * 263 + k]; }
  else         { if (k >= 257 && k < 263) v = pw1[(n - 256) * 6 + (k - 257)]; }
  W1T[idx] = (short)f2bf(v);
  if (idx < 512) b1big[idx] = (idx < 256) ? eb1[idx] : pb1[idx - 256];
}

__global__ __launch_bounds__(256) void prep_w2t(const float* __restrict__ ew2,
                                                const float* __restrict__ eww,
                                                const float* __restrict__ eb2,
                                                const float* __restrict__ ewb,
                                                const float* __restrict__ pw2,
                                                const float* __restrict__ pb2,
                                                short* __restrict__ W2T,
                                                float* __restrict__ biasC) {
  int idx = blockIdx.x * 256 + threadIdx.x;   // 16*512
  if (idx >= 16 * 512) return;
  int hh = idx >> 9, k = idx & 511;
  float v = 0.f;
  if (hh < 8) {
    if (k < 256) {
      float s = 0.f;
      for (int j = 0; j < 256; ++j) s += eww[hh * 256 + j] * ew2[j * 256 + k];
      v = s;
    } else {
      v = pw2[hh * 256 + (k - 256)];
    }
  }
  W2T[idx] = (short)f2bf(v);
  if (idx < 16) {
    float b = 0.f;
    if (idx < 8) {
      float s = 0.f;
      for (int j = 0; j < 256; ++j) s += eww[idx * 256 + j] * eb2[j];
      b = s + ewb[idx] + pb2[idx];
    }
    biasC[idx] = b;
  }
}

// wcomb [128][768] bf16 = [wo | cw3]; bcomb = bo + cb3
__global__ __launch_bounds__(256) void prep_wcomb(const float* __restrict__ wo,
                                                  const float* __restrict__ cw3,
                                                  const float* __restrict__ bo,
                                                  const float* __restrict__ cb3,
                                                  ushort* __restrict__ wcomb,
                                                  float* __restrict__ bcomb) {
  int idx = blockIdx.x * 256 + threadIdx.x;   // 128*768
  if (idx >= 128 * 768) return;
  int j = idx / 768, k = idx % 768;
  float v = (k < 512) ? wo[j * 512 + k] : cw3[j * 256 + (k - 512)];
  wcomb[idx] = f2bf(v);
  if (idx < 128) bcomb[idx] = bo[idx] + cb3[idx];
}

__global__ __launch_bounds__(256) void prep_cw2bf(const float* __restrict__ cw2,
                                                  ushort* __restrict__ cw2bf) {
  int idx = blockIdx.x * 256 + threadIdx.x;   // 256*256
  if (idx >= 256 * 256) return;
  cw2bf[idx] = f2bf(cw2[idx]);
}

// ---------- QKV via MFMA -> q bf16, k fp8, v bf16 ----------
__global__ __launch_bounds__(256) void qkv_mfma_kernel(
    const ushort* __restrict__ h_bf,    // [n][128]
    const ushort* __restrict__ wqkv,    // [1536][128]
    const float* __restrict__ bqkv,     // [1536]
    ushort* __restrict__ q_t, uchar* __restrict__ k8, ushort* __restrict__ v_t,
    int n)
{
  __shared__ float oS[64 * 68];
  int tid = threadIdx.x;
  int lane = tid & 63, w = tid >> 6;
  int l15 = lane & 15, l4 = lane >> 4;
  int m0 = blockIdx.x * 64;
  int jb = blockIdx.y;                 // 0..23
  int n0 = jb * 64 + w * 16;

  f32x4 acc[4];
#pragma unroll
  for (int mf = 0; mf < 4; ++mf) acc[mf] = (f32x4){0.f, 0.f, 0.f, 0.f};

#pragma unroll
  for (int ks = 0; ks < 4; ++ks) {
    bf16x8 bW = *(const bf16x8*)(wqkv + (size_t)(n0 + l15) * 128 + ks * 32 + l4 * 8);
#pragma unroll
    for (int mf = 0; mf < 4; ++mf) {
      int gr = m0 + mf * 16 + l15; if (gr >= n) gr = n - 1;
      bf16x8 aH = *(const bf16x8*)(h_bf + (size_t)gr * 128 + ks * 32 + l4 * 8);
      acc[mf] = __builtin_amdgcn_mfma_f32_16x16x32_bf16(aH, bW, acc[mf], 0, 0, 0);
    }
  }
#pragma unroll
  for (int mf = 0; mf < 4; ++mf)
#pragma unroll
    for (int i = 0; i < 4; ++i)
      oS[(mf * 16 + l4 * 4 + i) * 68 + w * 16 + l15] = acc[mf][i];
  __syncthreads();
  {
    int row = tid >> 2, cs = (tid & 3) * 16;
    int gr = m0 + row;
    if (gr < n) {
      int gc = jb * 64 + cs;
      int tbl = gc >> 9, cc = gc & 511;
      if (tbl == 1) {                         // K table: fp8
        uint w0 = 0, w1 = 0, w2 = 0, w3 = 0;
#pragma unroll
        for (int j = 0; j < 4; ++j) w0 |= ((uint)f2e4m3(oS[row * 68 + cs + j] + bqkv[gc + j])) << (8 * j);
#pragma unroll
        for (int j = 0; j < 4; ++j) w1 |= ((uint)f2e4m3(oS[row * 68 + cs + 4 + j] + bqkv[gc + 4 + j])) << (8 * j);
#pragma unroll
        for (int j = 0; j < 4; ++j) w2 |= ((uint)f2e4m3(oS[row * 68 + cs + 8 + j] + bqkv[gc + 8 + j])) << (8 * j);
#pragma unroll
        for (int j = 0; j < 4; ++j) w3 |= ((uint)f2e4m3(oS[row * 68 + cs + 12 + j] + bqkv[gc + 12 + j])) << (8 * j);
        uint4 st = {w0, w1, w2, w3};
        *(uint4*)(k8 + (size_t)gr * 512 + cc) = st;
      } else {
        ushort* base = (tbl == 0) ? q_t : v_t;
        ushort8 o0, o1;
#pragma unroll
        for (int j = 0; j < 8; ++j) o0[j] = f2bf(oS[row * 68 + cs + j] + bqkv[gc + j]);
#pragma unroll
        for (int j = 0; j < 8; ++j) o1[j] = f2bf(oS[row * 68 + cs + 8 + j] + bqkv[gc + 8 + j]);
        *(ushort8*)(base + (size_t)gr * 512 + cc) = o0;
        *(ushort8*)(base + (size_t)gr * 512 + cc + 8) = o1;
      }
    }
  }
}

// ---------- fused edge MLP + pos-enc via MFMA ----------
// scores[e][8] = silu(A[e][264] @ W1big) @ W2big + biasC
#define EB 64       // edges per block
#define AS 296      // A_lds stride (bf16)
#define TS 72       // t1 chunk stride (bf16)

__global__ __launch_bounds__(256, 2) void edge_mfma_kernel(
    const ushort* __restrict__ h_bf, const float* __restrict__ x,
    const int* __restrict__ ei, int E,
    const short* __restrict__ W1T, const float* __restrict__ b1big,
    const short* __restrict__ W2T, const float* __restrict__ biasC,
    float* __restrict__ scores)
{
  extern __shared__ char smem[];
  short* Albuf = (short*)smem;              // [EB][AS]
  short* T1    = Albuf + EB * AS;           // [4][EB][TS]
  float* slab  = (float*)smem;              // overlay: [4][EB][16] f32

  int tid = threadIdx.x;
  int lane = tid & 63, w = tid >> 6;
  int l15 = lane & 15, l4 = lane >> 4;
  int eb0 = blockIdx.x * EB;

  // ---- gather: 4 threads per edge ----
  {
    int e = tid >> 2, p = tid & 3;
    int eg = eb0 + e; if (eg >= E) eg = E - 1;
    int r = ei[eg], c = ei[E + eg];
    const ushort* hr = h_bf + (size_t)r * 128 + p * 32;
    const ushort* hc = h_bf + (size_t)c * 128 + p * 32;
    short* arow = Albuf + e * AS;
#pragma unroll
    for (int i = 0; i < 4; ++i)
      *(uint4*)(arow + p * 32 + i * 8) = *(const uint4*)(hr + i * 8);
#pragma unroll
    for (int i = 0; i < 4; ++i)
      *(uint4*)(arow + 128 + p * 32 + i * 8) = *(const uint4*)(hc + i * 8);
    if (p == 0) {
      float xr0 = x[r*3], xr1 = x[r*3+1], xr2 = x[r*3+2];
      float xc0 = x[c*3], xc1 = x[c*3+1], xc2 = x[c*3+2];
      float d0 = xr0-xc0, d1 = xr1-xc1, d2 = xr2-xc2;
      bf16x8 g;
      g[0] = (short)f2bf(d0*d0 + d1*d1 + d2*d2);
      g[1] = (short)f2bf(xr0); g[2] = (short)f2bf(xr1); g[3] = (short)f2bf(xr2);
      g[4] = (short)f2bf(xc0); g[5] = (short)f2bf(xc1); g[6] = (short)f2bf(xc2);
      g[7] = 0;
      *(bf16x8*)(arow + 256) = g;
    } else {
      bf16x8 z = {0,0,0,0,0,0,0,0};
      *(bf16x8*)(arow + 256 + p * 8) = z;
    }
  }
  __syncthreads();

  f32x4 sacc[4];
#pragma unroll
  for (int ef = 0; ef < 4; ++ef) sacc[ef] = (f32x4){0.f, 0.f, 0.f, 0.f};

  short* t1w = T1 + w * (EB * TS);

  // chunk 0: edge-MLP cols (n0 = w*64, full K); chunk 1: pos cols (n0 = 256+w*64, K-slice 8 only)
#pragma unroll
  for (int cch = 0; cch < 2; ++cch) {
    const int n0 = cch ? (256 + w * 64) : (w * 64);
    const int ks0 = cch ? 8 : 0;
    f32x4 acc[4][4];
#pragma unroll
    for (int mf = 0; mf < 4; ++mf)
#pragma unroll
      for (int ef = 0; ef < 4; ++ef) acc[mf][ef] = (f32x4){0.f, 0.f, 0.f, 0.f};

    for (int ks = ks0; ks < 9; ++ks) {
      bf16x8 aW[4], bE[4];
#pragma unroll
      for (int mf = 0; mf < 4; ++mf)
        aW[mf] = *(const bf16x8*)(W1T + (size_t)(n0 + mf * 16 + l15) * 288 + ks * 32 + l4 * 8);
#pragma unroll
      for (int ef = 0; ef < 4; ++ef)
        bE[ef] = *(const bf16x8*)(Albuf + (ef * 16 + l15) * AS + ks * 32 + l4 * 8);
#pragma unroll
      for (int mf = 0; mf < 4; ++mf)
#pragma unroll
        for (int ef = 0; ef < 4; ++ef)
          acc[mf][ef] = __builtin_amdgcn_mfma_f32_16x16x32_bf16(aW[mf], bE[ef], acc[mf][ef], 0, 0, 0);
    }
#pragma unroll
    for (int mf = 0; mf < 4; ++mf) {
      int nl = mf * 16 + l4 * 4;
      float4 bias = *(const float4*)(b1big + n0 + nl);
#pragma unroll
      for (int ef = 0; ef < 4; ++ef) {
        int e = ef * 16 + l15;
        f32x4 v = acc[mf][ef];
        float s0 = silu_fast(v[0] + bias.x);
        float s1 = silu_fast(v[1] + bias.y);
        float s2 = silu_fast(v[2] + bias.z);
        float s3 = silu_fast(v[3] + bias.w);
        uint2 pk;
        asm("v_cvt_pk_bf16_f32 %0, %1, %2" : "=v"(pk.x) : "v"(s0), "v"(s1));
        asm("v_cvt_pk_bf16_f32 %0, %1, %2" : "=v"(pk.y) : "v"(s2), "v"(s3));
        *(uint2*)(t1w + e * TS + nl) = pk;
      }
    }
#pragma unroll
    for (int ks2 = 0; ks2 < 2; ++ks2) {
      bf16x8 bW2 = *(const bf16x8*)(W2T + (size_t)l15 * 512 + n0 + ks2 * 32 + l4 * 8);
#pragma unroll
      for (int ef = 0; ef < 4; ++ef) {
        bf16x8 aT = *(const bf16x8*)(t1w + (ef * 16 + l15) * TS + ks2 * 32 + l4 * 8);
        sacc[ef] = __builtin_amdgcn_mfma_f32_16x16x32_bf16(aT, bW2, sacc[ef], 0, 0, 0);
      }
    }
  }
  __syncthreads();
#pragma unroll
  for (int ef = 0; ef < 4; ++ef)
#pragma unroll
    for (int i = 0; i < 4; ++i)
      slab[(w * EB + ef * 16 + l4 * 4 + i) * 16 + l15] = sacc[ef][i];
  __syncthreads();
  for (int t = tid; t < EB * 8; t += 256) {
    int e = t >> 3, hh = t & 7;
    float s = biasC[hh]
            + slab[(0 * EB + e) * 16 + hh] + slab[(1 * EB + e) * 16 + hh]
            + slab[(2 * EB + e) * 16 + hh] + slab[(3 * EB + e) * 16 + hh];
    if (eb0 + e < E) scores[(size_t)(eb0 + e) * 8 + hh] = s;
  }
}

// ---------- CSR build ----------
__global__ __launch_bounds__(256) void count_kernel(const int* __restrict__ ei,
                                                    int* __restrict__ cnt, int E) {
  int e = blockIdx.x * 256 + threadIdx.x;
  if (e < E) atomicAdd(&cnt[ei[e]], 1);
}

__global__ __launch_bounds__(1024) void scan_kernel(int* __restrict__ cnt,
                                                    int* __restrict__ offs, int n) {
  __shared__ int part[1024];
  int t = threadIdx.x;
  int chunk = (n + 1023) >> 10;
  int s = t * chunk, e = min(s + chunk, n);
  int sum = 0;
  for (int i = s; i < e; ++i) sum += cnt[i];
  part[t] = sum;
  __syncthreads();
  for (int off = 1; off < 1024; off <<= 1) {
    int v = (t >= off) ? part[t - off] : 0;
    __syncthreads();
    part[t] += v;
    __syncthreads();
  }
  int run = (t == 0) ? 0 : part[t - 1];
  for (int i = s; i < e; ++i) {
    int c = cnt[i];
    offs[i] = run;
    cnt[i] = run;     // becomes cursor
    run += c;
  }
  if (t == 1023) offs[n] = run;
}

__global__ __launch_bounds__(256) void fill_kernel(const int* __restrict__ ei,
                                                   int* __restrict__ cursor,
                                                   int2* __restrict__ pairs, int E) {
  int e = blockIdx.x * 256 + threadIdx.x;
  if (e < E) {
    int p = atomicAdd(&cursor[ei[e]], 1);
    pairs[p] = make_int2(e, ei[E + e]);
  }
}

// ---------- fused QK + softmax + aggregation (flash-style CSR, 1 wave/node) ----------
__global__ __launch_bounds__(256) void attn_fused_kernel(
    const int* __restrict__ offs,
    const int2* __restrict__ pairs,
    const int* __restrict__ mask,
    const float* __restrict__ scores,     // mlp+pos scores [E][8]
    const ushort* __restrict__ q_t,
    const uchar* __restrict__ k8,
    const ushort* __restrict__ v_t,
    ushort* __restrict__ agg, int n)
{
  int node = blockIdx.x * 4 + (threadIdx.x >> 6);
  if (node >= n) return;
  int lane = threadIdx.x & 63;          // head = lane>>3, dims (lane&7)*8..+8
  int start = offs[node], end = offs[node + 1];

  bf16x8 qv = *(const bf16x8*)(q_t + (size_t)node * 512 + lane * 8);
  float qf[8];
#pragma unroll
  for (int j = 0; j < 8; ++j) qf[j] = bf2f((ushort)qv[j]);

  float m = -3.0e38f, ssum = 0.f;
  float acc[8];
#pragma unroll
  for (int j = 0; j < 8; ++j) acc[j] = 0.f;

  for (int i = start; i < end; ++i) {
    int2 pr = pairs[i];
    int eid = pr.x, col = pr.y;
    uint2 kw = *(const uint2*)(k8 + (size_t)col * 512 + lane * 8);
    bf16x8 vv = *(const bf16x8*)(v_t + (size_t)col * 512 + lane * 8);
    float dot = 0.f;
#pragma unroll
    for (int j = 0; j < 4; ++j)
      dot = fmaf(qf[j], e4m3f((kw.x >> (8 * j)) & 0xffu), dot);
#pragma unroll
    for (int j = 0; j < 4; ++j)
      dot = fmaf(qf[4 + j], e4m3f((kw.y >> (8 * j)) & 0xffu), dot);
    dot += __shfl_xor(dot, 1);
    dot += __shfl_xor(dot, 2);
    dot += __shfl_xor(dot, 4);
    float sml = scores[(size_t)eid * 8 + (lane >> 3)];
    float s = mask[eid] ? fmaf(dot, 0.125f, sml) : -1e9f;
    if (s > m) {
      float scale = __expf(m - s);      // first edge: exp(-inf) = 0
      ssum *= scale;
#pragma unroll
      for (int j = 0; j < 8; ++j) acc[j] *= scale;
      m = s;
    }
    float e = __expf(s - m);
    ssum += e;
#pragma unroll
    for (int j = 0; j < 8; ++j) acc[j] = fmaf(e, bf2f((ushort)vv[j]), acc[j]);
  }
  float inv = 1.f / (ssum + 1e-8f);
  ushort8 ov;
#pragma unroll
  for (int j = 0; j < 8; ++j) ov[j] = f2bf(acc[j] * inv);
  *(ushort8*)(agg + (size_t)node * 512 + lane * 8) = ov;
}

// ---------- coord layer 1: c1[n][256] bf16 = silu(x @ cw1^T + cb1) ----------
__global__ __launch_bounds__(256) void coord_c1_kernel(const float* __restrict__ x,
                                                       const float* __restrict__ cw1,
                                                       const float* __restrict__ cb1,
                                                       ushort* __restrict__ c1, int n) {
  int idx = blockIdx.x * 256 + threadIdx.x;
  if (idx >= n * 256) return;
  int node = idx >> 8, j = idx & 255;
  float t = fmaf(x[node * 3 + 2], cw1[j * 3 + 2],
            fmaf(x[node * 3 + 1], cw1[j * 3 + 1],
            fmaf(x[node * 3 + 0], cw1[j * 3 + 0], cb1[j])));
  c1[idx] = f2bf(silu_fast(t));
}

// ---------- coord layer 2 via MFMA: c2 = silu(c1 @ cw2^T + cb2) bf16 ----------
__global__ __launch_bounds__(256) void c2_mfma_kernel(const ushort* __restrict__ c1,
                                                      const ushort* __restrict__ cw2bf,
                                                      const float* __restrict__ cb2,
                                                      ushort* __restrict__ c2, int n) {
  __shared__ float oS[64 * 68];
  int tid = threadIdx.x;
  int lane = tid & 63, w = tid >> 6;
  int l15 = lane & 15, l4 = lane >> 4;
  int m0 = blockIdx.x * 64;
  int n0 = blockIdx.y * 64 + w * 16;

  f32x4 acc[4];
#pragma unroll
  for (int mf = 0; mf < 4; ++mf) acc[mf] = (f32x4){0.f, 0.f, 0.f, 0.f};
#pragma unroll
  for (int ks = 0; ks < 8; ++ks) {
    bf16x8 bW = *(const bf16x8*)(cw2bf + (size_t)(n0 + l15) * 256 + ks * 32 + l4 * 8);
#pragma unroll
    for (int mf = 0; mf < 4; ++mf) {
      int gr = m0 + mf * 16 + l15; if (gr >= n) gr = n - 1;
      bf16x8 aH = *(const bf16x8*)(c1 + (size_t)gr * 256 + ks * 32 + l4 * 8);
      acc[mf] = __builtin_amdgcn_mfma_f32_16x16x32_bf16(aH, bW, acc[mf], 0, 0, 0);
    }
  }
#pragma unroll
  for (int mf = 0; mf < 4; ++mf)
#pragma unroll
    for (int i = 0; i < 4; ++i)
      oS[(mf * 16 + l4 * 4 + i) * 68 + w * 16 + l15] = acc[mf][i];
  __syncthreads();
  {
    int row = tid >> 2, cs = (tid & 3) * 16;
    int gr = m0 + row;
    if (gr < n) {
      int gc = blockIdx.y * 64 + cs;
      ushort8 o0, o1;
#pragma unroll
      for (int j = 0; j < 8; ++j) o0[j] = f2bf(silu_fast(oS[row * 68 + cs + j] + cb2[gc + j]));
#pragma unroll
      for (int j = 0; j < 8; ++j) o1[j] = f2bf(silu_fast(oS[row * 68 + cs + 8 + j] + cb2[gc + 8 + j]));
      *(ushort8*)(c2 + (size_t)gr * 256 + gc) = o0;
      *(ushort8*)(c2 + (size_t)gr * 256 + gc + 8) = o1;
    }
  }
}

// ---------- final fused out GEMM: out[n][128] = [agg|c2] @ wcomb^T + bcomb ----------
__global__ __launch_bounds__(256) void final_mfma_kernel(const ushort* __restrict__ agg,
                                                         const ushort* __restrict__ c2,
                                                         const ushort* __restrict__ wcomb,
                                                         const float* __restrict__ bcomb,
                                                         float* __restrict__ out, int n) {
  __shared__ float oS[64 * 68];
  int tid = threadIdx.x;
  int lane = tid & 63, w = tid >> 6;
  int l15 = lane & 15, l4 = lane >> 4;
  int m0 = blockIdx.x * 64;
  int jb = blockIdx.y;                  // 0..1
  int n0 = jb * 64 + w * 16;

  f32x4 acc[4];
#pragma unroll
  for (int mf = 0; mf < 4; ++mf) acc[mf] = (f32x4){0.f, 0.f, 0.f, 0.f};
#pragma unroll
  for (int ks = 0; ks < 24; ++ks) {
    bf16x8 bW = *(const bf16x8*)(wcomb + (size_t)(n0 + l15) * 768 + ks * 32 + l4 * 8);
#pragma unroll
    for (int mf = 0; mf < 4; ++mf) {
      int gr = m0 + mf * 16 + l15; if (gr >= n) gr = n - 1;
      const ushort* ap = (ks < 16) ? (agg + (size_t)gr * 512 + ks * 32)
                                   : (c2 + (size_t)gr * 256 + (ks - 16) * 32);
      bf16x8 aH = *(const bf16x8*)(ap + l4 * 8);
      acc[mf] = __builtin_amdgcn_mfma_f32_16x16x32_bf16(aH, bW, acc[mf], 0, 0, 0);
    }
  }
#pragma unroll
  for (int mf = 0; mf < 4; ++mf)
#pragma unroll
    for (int i = 0; i < 4; ++i)
      oS[(mf * 16 + l4 * 4 + i) * 68 + w * 16 + l15] = acc[mf][i];
  __syncthreads();
  {
    int row = tid >> 2, cs = (tid & 3) * 16;
    int gr = m0 + row;
    if (gr < n) {
      int gc = jb * 64 + cs;
#pragma unroll
      for (int g = 0; g < 4; ++g) {
        float4 o;
        o.x = oS[row * 68 + cs + g * 4 + 0] + bcomb[gc + g * 4 + 0];
        o.y = oS[row * 68 + cs + g * 4 + 1] + bcomb[gc + g * 4 + 1];
        o.z = oS[row * 68 + cs + g * 4 + 2] + bcomb[gc + g * 4 + 2];
        o.w = oS[row * 68 + cs + g * 4 + 3] + bcomb[gc + g * 4 + 3];
        *(float4*)(out + (size_t)gr * 128 + gc + g * 4) = o;
      }
    }
  }
}

// ---------- launch ----------
extern "C" void kernel_launch(void* const* d_in, const int* in_sizes, int n_in,
                              void* d_out, int out_size, void* d_ws, size_t ws_size,
                              hipStream_t stream) {
  const float* h   = (const float*)d_in[0];
  const float* x   = (const float*)d_in[1];
  const int*   ei  = (const int*)d_in[2];
  const int*   mask= (const int*)d_in[3];
  const float* wq  = (const float*)d_in[4];
  const float* bq  = (const float*)d_in[5];
  const float* wk  = (const float*)d_in[6];
  const float* bk  = (const float*)d_in[7];
  const float* wv  = (const float*)d_in[8];
  const float* bv  = (const float*)d_in[9];
  const float* wo  = (const float*)d_in[10];
  const float* bo  = (const float*)d_in[11];
  const float* pw1 = (const float*)d_in[12];
  const float* pb1 = (const float*)d_in[13];
  const float* pw2 = (const float*)d_in[14];
  const float* pb2 = (const float*)d_in[15];
  const float* ew1 = (const float*)d_in[16];
  const float* eb1 = (const float*)d_in[17];
  const float* ew2 = (const float*)d_in[18];
  const float* eb2 = (const float*)d_in[19];
  const float* eww = (const float*)d_in[20];
  const float* ewb = (const float*)d_in[21];
  const float* cw1 = (const float*)d_in[22];
  const float* cb1 = (const float*)d_in[23];
  const float* cw2 = (const float*)d_in[24];
  const float* cb2 = (const float*)d_in[25];
  const float* cw3 = (const float*)d_in[26];
  const float* cb3 = (const float*)d_in[27];

  int n = in_sizes[0] / 128;
  int E = in_sizes[3];

  char* wptr = (char*)d_ws;
  auto alloc = [&](size_t bytes) {
    char* p = wptr;
    wptr += (bytes + 255) & ~(size_t)255;
    return p;
  };
  ushort* q_t   = (ushort*)alloc((size_t)n * 512 * 2);
  uchar*  k8    = (uchar*)alloc((size_t)n * 512);
  ushort* v_t   = (ushort*)alloc((size_t)n * 512 * 2);
  ushort* h_bf  = (ushort*)alloc((size_t)n * 128 * 2);
  float* scores = (float*)alloc((size_t)E * 8 * 4);
  ushort* agg   = (ushort*)alloc((size_t)n * 512 * 2);
  ushort* c1    = (ushort*)alloc((size_t)n * 256 * 2);
  ushort* c2    = (ushort*)alloc((size_t)n * 256 * 2);
  ushort* wqkv  = (ushort*)alloc((size_t)1536 * 128 * 2);
  float* bqkv   = (float*)alloc((size_t)1536 * 4);
  short* W1T    = (short*)alloc((size_t)512 * 288 * 2);
  float* b1big  = (float*)alloc((size_t)512 * 4);
  short* W2T    = (short*)alloc((size_t)16 * 512 * 2);
  float* biasC  = (float*)alloc((size_t)16 * 4);
  ushort* wcomb = (ushort*)alloc((size_t)128 * 768 * 2);
  float* bcomb  = (float*)alloc((size_t)128 * 4);
  ushort* cw2bf = (ushort*)alloc((size_t)256 * 256 * 2);
  int* offs     = (int*)alloc((size_t)(n + 1) * 4);
  int* cursor   = (int*)alloc((size_t)n * 4);
  int2* pairs   = (int2*)alloc((size_t)E * 8);

  hipMemsetAsync(cursor, 0, (size_t)n * 4, stream);

  h2bf_kernel<<<dim3((n * 128 / 4 + 255) / 256), 256, 0, stream>>>(h, h_bf, n * 128);
  prep_wqkv<<<dim3((1536 * 128 + 255) / 256), 256, 0, stream>>>(wq, wk, wv, bq, bk, bv, wqkv, bqkv);
  prep_w1t<<<dim3((512 * 288 + 255) / 256), 256, 0, stream>>>(ew1, eb1, pw1, pb1, W1T, b1big);
  prep_w2t<<<dim3((16 * 512 + 255) / 256), 256, 0, stream>>>(ew2, eww, eb2, ewb, pw2, pb2, W2T, biasC);
  prep_wcomb<<<dim3((128 * 768 + 255) / 256), 256, 0, stream>>>(wo, cw3, bo, cb3, wcomb, bcomb);
  prep_cw2bf<<<dim3((256 * 256 + 255) / 256), 256, 0, stream>>>(cw2, cw2bf);

  qkv_mfma_kernel<<<dim3((n + 63) / 64, 24), 256, 0, stream>>>(h_bf, wqkv, bqkv, q_t, k8, v_t, n);

  size_t edge_lds = (size_t)(EB * AS + 4 * EB * TS) * 2;   // 74752 B
  edge_mfma_kernel<<<dim3((E + EB - 1) / EB), 256, edge_lds, stream>>>(
      h_bf, x, ei, E, W1T, b1big, W2T, biasC, scores);

  count_kernel<<<dim3((E + 255) / 256), 256, 0, stream>>>(ei, cursor, E);
  scan_kernel<<<dim3(1), 1024, 0, stream>>>(cursor, offs, n);
  fill_kernel<<<dim3((E + 255) / 256), 256, 0, stream>>>(ei, cursor, pairs, E);

  attn_fused_kernel<<<dim3((n + 3) / 4), 256, 0, stream>>>(
      offs, pairs, mask, scores, q_t, k8, v_t, agg, n);

  coord_c1_kernel<<<dim3((n * 256 + 255) / 256), 256, 0, stream>>>(x, cw1, cb1, c1, n);
  c2_mfma_kernel<<<dim3((n + 63) / 64, 4), 256, 0, stream>>>(c1, cw2bf, cb2, c2, n);

  hipMemsetAsync((float*)d_out + (size_t)n * 128, 0, (size_t)n * 3 * 4, stream);
  final_mfma_kernel<<<dim3((n + 63) / 64, 2), 256, 0, stream>>>(agg, c2, wcomb, bcomb,
                                                                (float*)d_out, n);
}

// Round 5
// 701.030 us; speedup vs baseline: 5.7251x; 1.0142x over previous
//
#include <hip/hip_runtime.h>

typedef unsigned int uint;
typedef unsigned short ushort;
typedef unsigned char uchar;
typedef __attribute__((ext_vector_type(8))) short bf16x8;
typedef __attribute__((ext_vector_type(8))) ushort ushort8;
typedef __attribute__((ext_vector_type(4))) float f32x4;

// ---------- helpers ----------
__device__ __forceinline__ float silu_fast(float t) {
  return t * __builtin_amdgcn_rcpf(1.f + __expf(-t));
}
__device__ __forceinline__ float bf2f(ushort u) {
  union { uint i; float f; } v; v.i = ((uint)u) << 16; return v.f;
}
__device__ __forceinline__ ushort f2bf(float f) {
  union { float f; uint i; } v; v.f = f;
  uint r = (v.i + 0x7fffu + ((v.i >> 16) & 1u)) >> 16;
  return (ushort)r;
}
// fp8 e4m3 (OCP) encode, RNE, sat-to-448
__device__ __forceinline__ uchar f2e4m3(float f) {
  uint u = __float_as_uint(f);
  uint s = (u >> 24) & 0x80u;
  uint m = u & 0x7fffffffu;
  if (m >= 0x43f00000u) return (uchar)(s | 0x7e);
  if (m >= 0x3c800000u) {
    uint r = m + 0x7ffffu + ((m >> 20) & 1u);
    uint e = (r >> 23) - 120u;
    if (e > 15u) return (uchar)(s | 0x7e);
    return (uchar)(s | (e << 3) | ((r >> 20) & 7u));
  }
  float az = __uint_as_float(m);
  uint k = (uint)__float2int_rn(az * 512.f);
  return (uchar)(s | k);
}
__device__ __forceinline__ float e4m3f(uint b) {
  uint u = ((b & 0x80u) << 24) | ((b & 0x7fu) << 20);
  return __uint_as_float(u) * 0x1p+120f;
}

// ---------- mega prep: h2bf | c1 | wqkv | w1t | w2t | wcomb | cw2bf | count ----------
__global__ __launch_bounds__(256) void mega_prep(
    const float* __restrict__ h, const float* __restrict__ x,
    const int* __restrict__ ei,
    const float* __restrict__ wq, const float* __restrict__ wk, const float* __restrict__ wv,
    const float* __restrict__ bq, const float* __restrict__ bk, const float* __restrict__ bv,
    const float* __restrict__ ew1, const float* __restrict__ eb1,
    const float* __restrict__ pw1, const float* __restrict__ pb1,
    const float* __restrict__ ew2, const float* __restrict__ eww,
    const float* __restrict__ eb2, const float* __restrict__ ewb,
    const float* __restrict__ pw2, const float* __restrict__ pb2,
    const float* __restrict__ wo, const float* __restrict__ cw3,
    const float* __restrict__ bo, const float* __restrict__ cb3,
    const float* __restrict__ cw1, const float* __restrict__ cb1,
    const float* __restrict__ cw2,
    ushort* __restrict__ h_bf, ushort* __restrict__ c1,
    ushort* __restrict__ wqkv, float* __restrict__ bqkv,
    short* __restrict__ W1T, float* __restrict__ b1big,
    short* __restrict__ W2T, float* __restrict__ biasC,
    ushort* __restrict__ wcomb, float* __restrict__ bcomb,
    ushort* __restrict__ cw2bf, int* __restrict__ cnt,
    int n, int E,
    int o1, int o2, int o3, int o4, int o5, int o6, int o7)
{
  int b = blockIdx.x, tid = threadIdx.x;
  if (b < o1) {                       // h -> bf16, 4/thread
    int idx = b * 256 + tid;
    if (idx * 4 < n * 128) {
      float4 v = *(const float4*)(h + idx * 4);
      ushort4 o; o.x = f2bf(v.x); o.y = f2bf(v.y); o.z = f2bf(v.z); o.w = f2bf(v.w);
      *(ushort4*)(h_bf + idx * 4) = o;
    }
  } else if (b < o2) {                // c1 = silu(x@cw1^T+cb1) bf16
    int idx = (b - o1) * 256 + tid;
    if (idx < n * 256) {
      int node = idx >> 8, j = idx & 255;
      float t = fmaf(x[node * 3 + 2], cw1[j * 3 + 2],
                fmaf(x[node * 3 + 1], cw1[j * 3 + 1],
                fmaf(x[node * 3 + 0], cw1[j * 3 + 0], cb1[j])));
      c1[idx] = f2bf(silu_fast(t));
    }
  } else if (b < o3) {                // wqkv bf16 + bqkv
    int idx = (b - o2) * 256 + tid;
    if (idx < 1536 * 128) {
      int j = idx >> 7, k = idx & 127;
      float v = (j < 512) ? wq[j * 128 + k]
              : (j < 1024) ? wk[(j - 512) * 128 + k]
              : wv[(j - 1024) * 128 + k];
      wqkv[idx] = f2bf(v);
      if (idx < 1536)
        bqkv[idx] = (idx < 512) ? bq[idx] : (idx < 1024) ? bk[idx - 512] : bv[idx - 1024];
    }
  } else if (b < o4) {                // W1T [512][288]
    int idx = (b - o3) * 256 + tid;
    if (idx < 512 * 288) {
      int nn = idx / 288, k = idx % 288;
      float v = 0.f;
      if (nn < 256) { if (k < 263) v = ew1[nn * 263 + k]; }
      else          { if (k >= 257 && k < 263) v = pw1[(nn - 256) * 6 + (k - 257)]; }
      W1T[idx] = (short)f2bf(v);
      if (idx < 512) b1big[idx] = (idx < 256) ? eb1[idx] : pb1[idx - 256];
    }
  } else if (b < o5) {                // W2T [16][512] + biasC
    int idx = (b - o4) * 256 + tid;
    if (idx < 16 * 512) {
      int hh = idx >> 9, k = idx & 511;
      float v = 0.f;
      if (hh < 8) {
        if (k < 256) {
          float s = 0.f;
          for (int j = 0; j < 256; ++j) s += eww[hh * 256 + j] * ew2[j * 256 + k];
          v = s;
        } else v = pw2[hh * 256 + (k - 256)];
      }
      W2T[idx] = (short)f2bf(v);
      if (idx < 16) {
        float bb = 0.f;
        if (idx < 8) {
          float s = 0.f;
          for (int j = 0; j < 256; ++j) s += eww[idx * 256 + j] * eb2[j];
          bb = s + ewb[idx] + pb2[idx];
        }
        biasC[idx] = bb;
      }
    }
  } else if (b < o6) {                // wcomb [128][768] + bcomb
    int idx = (b - o5) * 256 + tid;
    if (idx < 128 * 768) {
      int j = idx / 768, k = idx % 768;
      float v = (k < 512) ? wo[j * 512 + k] : cw3[j * 256 + (k - 512)];
      wcomb[idx] = f2bf(v);
      if (idx < 128) bcomb[idx] = bo[idx] + cb3[idx];
    }
  } else if (b < o7) {                // cw2 bf16
    int idx = (b - o6) * 256 + tid;
    if (idx < 256 * 256) cw2bf[idx] = f2bf(cw2[idx]);
  } else {                            // count (CSR degree)
    int e = (b - o7) * 256 + tid;
    if (e < E) atomicAdd(&cnt[ei[e]], 1);
  }
}

// ---------- QKV via swapped MFMA, jb-loop inside block ----------
__global__ __launch_bounds__(256) void qkv_mfma2_kernel(
    const ushort* __restrict__ h_bf,    // [n][128]
    const ushort* __restrict__ wqkv,    // [1536][128]
    const float* __restrict__ bqkv,     // [1536]
    ushort* __restrict__ q_t, uchar* __restrict__ k8, ushort* __restrict__ v_t,
    int n)
{
  int tid = threadIdx.x;
  int lane = tid & 63, w = tid >> 6;
  int l15 = lane & 15, l4 = lane >> 4;
  int m0 = blockIdx.x * 64;
  int mrow = m0 + w * 16 + l15;         // this lane's output node (column of D)
  bool valid = mrow < n;
  int mr = valid ? mrow : (n - 1);

  bf16x8 hf[4];
#pragma unroll
  for (int ks = 0; ks < 4; ++ks)
    hf[ks] = *(const bf16x8*)(h_bf + (size_t)mr * 128 + ks * 32 + l4 * 8);

  for (int jb = 0; jb < 24; ++jb) {
    f32x4 acc[4];
#pragma unroll
    for (int nf = 0; nf < 4; ++nf) acc[nf] = (f32x4){0.f, 0.f, 0.f, 0.f};
#pragma unroll
    for (int nf = 0; nf < 4; ++nf)
#pragma unroll
      for (int ks = 0; ks < 4; ++ks) {
        bf16x8 wf = *(const bf16x8*)(wqkv + (size_t)(jb * 64 + nf * 16 + l15) * 128 + ks * 32 + l4 * 8);
        acc[nf] = __builtin_amdgcn_mfma_f32_16x16x32_bf16(wf, hf[ks], acc[nf], 0, 0, 0);
      }
    if (valid) {
#pragma unroll
      for (int nf = 0; nf < 4; ++nf) {
        int gc = jb * 64 + nf * 16 + l4 * 4;
        float4 bb = *(const float4*)(bqkv + gc);
        float v0 = acc[nf][0] + bb.x, v1 = acc[nf][1] + bb.y;
        float v2 = acc[nf][2] + bb.z, v3 = acc[nf][3] + bb.w;
        if (jb < 8) {
          ushort4 st; st.x = f2bf(v0); st.y = f2bf(v1); st.z = f2bf(v2); st.w = f2bf(v3);
          *(ushort4*)(q_t + (size_t)mrow * 512 + gc) = st;
        } else if (jb < 16) {
          uint pk = (uint)f2e4m3(v0) | ((uint)f2e4m3(v1) << 8)
                  | ((uint)f2e4m3(v2) << 16) | ((uint)f2e4m3(v3) << 24);
          *(uint*)(k8 + (size_t)mrow * 512 + (gc - 512)) = pk;
        } else {
          ushort4 st; st.x = f2bf(v0); st.y = f2bf(v1); st.z = f2bf(v2); st.w = f2bf(v3);
          *(ushort4*)(v_t + (size_t)mrow * 512 + (gc - 1024)) = st;
        }
      }
    }
  }
}

// ---------- fused edge MLP + pos-enc via MFMA, direct-global B-frags ----------
// scores[e][8] = silu(A[e][264] @ W1big) @ W2big + biasC
#define EB 64
#define GS 32       // geom stride (shorts)
#define TS 72       // t1 stride (shorts)

__global__ __launch_bounds__(256, 4) void edge_mfma2_kernel(
    const ushort* __restrict__ h_bf, const float* __restrict__ x,
    const int* __restrict__ ei, int E,
    const short* __restrict__ W1T, const float* __restrict__ b1big,
    const short* __restrict__ W2T, const float* __restrict__ biasC,
    float* __restrict__ scores)
{
  __shared__ short geomL[EB * GS];      // 4 KB
  __shared__ short T1[4 * EB * TS];     // 36,864 B  (total 40,960 -> 4 blocks/CU)
  float* slab = (float*)T1;             // overlay after layer2 (16 KB)

  int tid = threadIdx.x;
  int lane = tid & 63, w = tid >> 6;
  int l15 = lane & 15, l4 = lane >> 4;
  int eb0 = blockIdx.x * EB;

  // ---- geom staging (1 thread/edge) ----
  if (tid < EB) {
    int eg = min(eb0 + tid, E - 1);
    int r = ei[eg], c = ei[E + eg];
    float xr0 = x[r*3], xr1 = x[r*3+1], xr2 = x[r*3+2];
    float xc0 = x[c*3], xc1 = x[c*3+1], xc2 = x[c*3+2];
    float d0 = xr0-xc0, d1 = xr1-xc1, d2 = xr2-xc2;
    bf16x8 g;
    g[0] = (short)f2bf(d0*d0 + d1*d1 + d2*d2);
    g[1] = (short)f2bf(xr0); g[2] = (short)f2bf(xr1); g[3] = (short)f2bf(xr2);
    g[4] = (short)f2bf(xc0); g[5] = (short)f2bf(xc1); g[6] = (short)f2bf(xc2);
    g[7] = 0;
    bf16x8 z = {0,0,0,0,0,0,0,0};
    *(bf16x8*)(geomL + tid * GS) = g;
    *(bf16x8*)(geomL + tid * GS + 8) = z;
    *(bf16x8*)(geomL + tid * GS + 16) = z;
    *(bf16x8*)(geomL + tid * GS + 24) = z;
  }
  __syncthreads();

  // per-lane edge node byte offsets (h_bf rows); one VGPR each, ks folds into imm
  const char* hb = (const char*)h_bf;
  uint ro[4], co[4], ga[4];
#pragma unroll
  for (int ef = 0; ef < 4; ++ef) {
    int eg = min(eb0 + ef * 16 + l15, E - 1);
    int r = ei[eg], c = ei[E + eg];
    ro[ef] = (uint)r * 256 + l4 * 16;
    co[ef] = (uint)c * 256 + l4 * 16;
    ga[ef] = (uint)(ef * 16 + l15) * (GS * 2) + l4 * 16;   // geom byte addr
  }

  f32x4 sacc[4];
#pragma unroll
  for (int ef = 0; ef < 4; ++ef) sacc[ef] = (f32x4){0.f, 0.f, 0.f, 0.f};

  short* t1w = T1 + w * (EB * TS);

#pragma unroll
  for (int cch = 0; cch < 2; ++cch) {
    const int n0 = cch ? (256 + w * 64) : (w * 64);
    const int ks0 = cch ? 8 : 0;
    f32x4 acc[4][4];
#pragma unroll
    for (int mf = 0; mf < 4; ++mf)
#pragma unroll
      for (int ef = 0; ef < 4; ++ef) acc[mf][ef] = (f32x4){0.f, 0.f, 0.f, 0.f};

#pragma unroll
    for (int ks = ks0; ks < 9; ++ks) {
      bf16x8 aW[4], bE[4];
#pragma unroll
      for (int mf = 0; mf < 4; ++mf)
        aW[mf] = *(const bf16x8*)(W1T + (size_t)(n0 + mf * 16 + l15) * 288 + ks * 32 + l4 * 8);
#pragma unroll
      for (int ef = 0; ef < 4; ++ef) {
        if (ks < 4)      bE[ef] = *(const bf16x8*)(hb + ro[ef] + ks * 64);
        else if (ks < 8) bE[ef] = *(const bf16x8*)(hb + co[ef] + (ks - 4) * 64);
        else             bE[ef] = *(const bf16x8*)((const char*)geomL + ga[ef]);
      }
#pragma unroll
      for (int mf = 0; mf < 4; ++mf)
#pragma unroll
        for (int ef = 0; ef < 4; ++ef)
          acc[mf][ef] = __builtin_amdgcn_mfma_f32_16x16x32_bf16(aW[mf], bE[ef], acc[mf][ef], 0, 0, 0);
    }
    // bias + silu + packed t1 store
#pragma unroll
    for (int mf = 0; mf < 4; ++mf) {
      int nl = mf * 16 + l4 * 4;
      float4 bias = *(const float4*)(b1big + n0 + nl);
#pragma unroll
      for (int ef = 0; ef < 4; ++ef) {
        int e = ef * 16 + l15;
        f32x4 v = acc[mf][ef];
        float s0 = silu_fast(v[0] + bias.x);
        float s1 = silu_fast(v[1] + bias.y);
        float s2 = silu_fast(v[2] + bias.z);
        float s3 = silu_fast(v[3] + bias.w);
        uint2 pk;
        asm("v_cvt_pk_bf16_f32 %0, %1, %2" : "=v"(pk.x) : "v"(s0), "v"(s1));
        asm("v_cvt_pk_bf16_f32 %0, %1, %2" : "=v"(pk.y) : "v"(s2), "v"(s3));
        *(uint2*)(t1w + e * TS + nl) = pk;
      }
    }
    // layer2 partial over this 64-col chunk
#pragma unroll
    for (int ks2 = 0; ks2 < 2; ++ks2) {
      bf16x8 bW2 = *(const bf16x8*)(W2T + (size_t)l15 * 512 + n0 + ks2 * 32 + l4 * 8);
#pragma unroll
      for (int ef = 0; ef < 4; ++ef) {
        bf16x8 aT = *(const bf16x8*)(t1w + (ef * 16 + l15) * TS + ks2 * 32 + l4 * 8);
        sacc[ef] = __builtin_amdgcn_mfma_f32_16x16x32_bf16(aT, bW2, sacc[ef], 0, 0, 0);
      }
    }
  }
  __syncthreads();    // all layer2 reads done; overlay slab on T1
#pragma unroll
  for (int ef = 0; ef < 4; ++ef)
#pragma unroll
    for (int i = 0; i < 4; ++i)
      slab[(w * EB + ef * 16 + l4 * 4 + i) * 16 + l15] = sacc[ef][i];
  __syncthreads();
  for (int t = tid; t < EB * 8; t += 256) {
    int e = t >> 3, hh = t & 7;
    float s = biasC[hh]
            + slab[(0 * EB + e) * 16 + hh] + slab[(1 * EB + e) * 16 + hh]
            + slab[(2 * EB + e) * 16 + hh] + slab[(3 * EB + e) * 16 + hh];
    if (eb0 + e < E) scores[(size_t)(eb0 + e) * 8 + hh] = s;
  }
}

// ---------- CSR scan + fill ----------
__global__ __launch_bounds__(1024) void scan_kernel(int* __restrict__ cnt,
                                                    int* __restrict__ offs, int n) {
  __shared__ int part[1024];
  int t = threadIdx.x;
  int chunk = (n + 1023) >> 10;
  int s = t * chunk, e = min(s + chunk, n);
  int sum = 0;
  for (int i = s; i < e; ++i) sum += cnt[i];
  part[t] = sum;
  __syncthreads();
  for (int off = 1; off < 1024; off <<= 1) {
    int v = (t >= off) ? part[t - off] : 0;
    __syncthreads();
    part[t] += v;
    __syncthreads();
  }
  int run = (t == 0) ? 0 : part[t - 1];
  for (int i = s; i < e; ++i) {
    int c = cnt[i];
    offs[i] = run;
    cnt[i] = run;
    run += c;
  }
  if (t == 1023) offs[n] = run;
}

__global__ __launch_bounds__(256) void fill_kernel(const int* __restrict__ ei,
                                                   int* __restrict__ cursor,
                                                   int2* __restrict__ pairs, int E) {
  int e = blockIdx.x * 256 + threadIdx.x;
  if (e < E) {
    int p = atomicAdd(&cursor[ei[e]], 1);
    pairs[p] = make_int2(e, ei[E + e]);
  }
}

// ---------- fused QK + softmax + aggregation (branchless + pipelined) ----------
__global__ __launch_bounds__(256) void attn_fused_kernel(
    const int* __restrict__ offs,
    const int2* __restrict__ pairs,
    const int* __restrict__ mask,
    const float* __restrict__ scores,
    const ushort* __restrict__ q_t,
    const uchar* __restrict__ k8,
    const ushort* __restrict__ v_t,
    ushort* __restrict__ agg, int n)
{
  int node = blockIdx.x * 4 + (threadIdx.x >> 6);
  if (node >= n) return;
  int lane = threadIdx.x & 63;
  int start = offs[node], end = offs[node + 1];

  bf16x8 qv = *(const bf16x8*)(q_t + (size_t)node * 512 + lane * 8);
  float qf[8];
#pragma unroll
  for (int j = 0; j < 8; ++j) qf[j] = bf2f((ushort)qv[j]);

  float m = -3.0e38f, ssum = 0.f;
  float acc[8];
#pragma unroll
  for (int j = 0; j < 8; ++j) acc[j] = 0.f;

  if (start < end) {
    int2 pr = pairs[start];
    uint2 kw = *(const uint2*)(k8 + (size_t)pr.y * 512 + lane * 8);
    bf16x8 vv = *(const bf16x8*)(v_t + (size_t)pr.y * 512 + lane * 8);
    float sml = scores[(size_t)pr.x * 8 + (lane >> 3)];
    int mk = mask[pr.x];

    for (int i = start; i < end; ++i) {
      uint2 kwc = kw; bf16x8 vvc = vv; float smlc = sml; int mkc = mk;
      int inx = (i + 1 < end) ? (i + 1) : i;
      pr = pairs[inx];
      kw = *(const uint2*)(k8 + (size_t)pr.y * 512 + lane * 8);
      vv = *(const bf16x8*)(v_t + (size_t)pr.y * 512 + lane * 8);
      sml = scores[(size_t)pr.x * 8 + (lane >> 3)];
      mk = mask[pr.x];

      float dot = 0.f;
#pragma unroll
      for (int j = 0; j < 4; ++j)
        dot = fmaf(qf[j], e4m3f((kwc.x >> (8 * j)) & 0xffu), dot);
#pragma unroll
      for (int j = 0; j < 4; ++j)
        dot = fmaf(qf[4 + j], e4m3f((kwc.y >> (8 * j)) & 0xffu), dot);
      dot += __shfl_xor(dot, 1);
      dot += __shfl_xor(dot, 2);
      dot += __shfl_xor(dot, 4);
      float s = mkc ? fmaf(dot, 0.125f, smlc) : -1e9f;
      float nm = fmaxf(m, s);
      float cs = __expf(m - nm);
      float e  = __expf(s - nm);
      ssum = fmaf(ssum, cs, e);
#pragma unroll
      for (int j = 0; j < 8; ++j)
        acc[j] = fmaf(acc[j], cs, e * bf2f((ushort)vvc[j]));
      m = nm;
    }
  }
  float inv = __builtin_amdgcn_rcpf(ssum + 1e-8f);
  ushort8 ov;
#pragma unroll
  for (int j = 0; j < 8; ++j) ov[j] = f2bf(acc[j] * inv);
  *(ushort8*)(agg + (size_t)node * 512 + lane * 8) = ov;
}

// ---------- coord layer 2 via MFMA: c2 = silu(c1 @ cw2^T + cb2) bf16 ----------
__global__ __launch_bounds__(256) void c2_mfma_kernel(const ushort* __restrict__ c1,
                                                      const ushort* __restrict__ cw2bf,
                                                      const float* __restrict__ cb2,
                                                      ushort* __restrict__ c2, int n) {
  __shared__ float oS[64 * 68];
  int tid = threadIdx.x;
  int lane = tid & 63, w = tid >> 6;
  int l15 = lane & 15, l4 = lane >> 4;
  int m0 = blockIdx.x * 64;
  int n0 = blockIdx.y * 64 + w * 16;

  f32x4 acc[4];
#pragma unroll
  for (int mf = 0; mf < 4; ++mf) acc[mf] = (f32x4){0.f, 0.f, 0.f, 0.f};
#pragma unroll
  for (int ks = 0; ks < 8; ++ks) {
    bf16x8 bW = *(const bf16x8*)(cw2bf + (size_t)(n0 + l15) * 256 + ks * 32 + l4 * 8);
#pragma unroll
    for (int mf = 0; mf < 4; ++mf) {
      int gr = m0 + mf * 16 + l15; if (gr >= n) gr = n - 1;
      bf16x8 aH = *(const bf16x8*)(c1 + (size_t)gr * 256 + ks * 32 + l4 * 8);
      acc[mf] = __builtin_amdgcn_mfma_f32_16x16x32_bf16(aH, bW, acc[mf], 0, 0, 0);
    }
  }
#pragma unroll
  for (int mf = 0; mf < 4; ++mf)
#pragma unroll
    for (int i = 0; i < 4; ++i)
      oS[(mf * 16 + l4 * 4 + i) * 68 + w * 16 + l15] = acc[mf][i];
  __syncthreads();
  {
    int row = tid >> 2, cs = (tid & 3) * 16;
    int gr = m0 + row;
    if (gr < n) {
      int gc = blockIdx.y * 64 + cs;
      ushort8 o0, o1;
#pragma unroll
      for (int j = 0; j < 8; ++j) o0[j] = f2bf(silu_fast(oS[row * 68 + cs + j] + cb2[gc + j]));
#pragma unroll
      for (int j = 0; j < 8; ++j) o1[j] = f2bf(silu_fast(oS[row * 68 + cs + 8 + j] + cb2[gc + 8 + j]));
      *(ushort8*)(c2 + (size_t)gr * 256 + gc) = o0;
      *(ushort8*)(c2 + (size_t)gr * 256 + gc + 8) = o1;
    }
  }
}

// ---------- final fused out GEMM: out[n][128] = [agg|c2] @ wcomb^T + bcomb ----------
__global__ __launch_bounds__(256) void final_mfma_kernel(const ushort* __restrict__ agg,
                                                         const ushort* __restrict__ c2,
                                                         const ushort* __restrict__ wcomb,
                                                         const float* __restrict__ bcomb,
                                                         float* __restrict__ out, int n) {
  __shared__ float oS[64 * 68];
  int tid = threadIdx.x;
  int lane = tid & 63, w = tid >> 6;
  int l15 = lane & 15, l4 = lane >> 4;
  int m0 = blockIdx.x * 64;
  int jb = blockIdx.y;
  int n0 = jb * 64 + w * 16;

  f32x4 acc[4];
#pragma unroll
  for (int mf = 0; mf < 4; ++mf) acc[mf] = (f32x4){0.f, 0.f, 0.f, 0.f};
#pragma unroll
  for (int ks = 0; ks < 24; ++ks) {
    bf16x8 bW = *(const bf16x8*)(wcomb + (size_t)(n0 + l15) * 768 + ks * 32 + l4 * 8);
#pragma unroll
    for (int mf = 0; mf < 4; ++mf) {
      int gr = m0 + mf * 16 + l15; if (gr >= n) gr = n - 1;
      const ushort* ap = (ks < 16) ? (agg + (size_t)gr * 512 + ks * 32)
                                   : (c2 + (size_t)gr * 256 + (ks - 16) * 32);
      bf16x8 aH = *(const bf16x8*)(ap + l4 * 8);
      acc[mf] = __builtin_amdgcn_mfma_f32_16x16x32_bf16(aH, bW, acc[mf], 0, 0, 0);
    }
  }
#pragma unroll
  for (int mf = 0; mf < 4; ++mf)
#pragma unroll
    for (int i = 0; i < 4; ++i)
      oS[(mf * 16 + l4 * 4 + i) * 68 + w * 16 + l15] = acc[mf][i];
  __syncthreads();
  {
    int row = tid >> 2, cs = (tid & 3) * 16;
    int gr = m0 + row;
    if (gr < n) {
      int gc = jb * 64 + cs;
#pragma unroll
      for (int g = 0; g < 4; ++g) {
        float4 o;
        o.x = oS[row * 68 + cs + g * 4 + 0] + bcomb[gc + g * 4 + 0];
        o.y = oS[row * 68 + cs + g * 4 + 1] + bcomb[gc + g * 4 + 1];
        o.z = oS[row * 68 + cs + g * 4 + 2] + bcomb[gc + g * 4 + 2];
        o.w = oS[row * 68 + cs + g * 4 + 3] + bcomb[gc + g * 4 + 3];
        *(float4*)(out + (size_t)gr * 128 + gc + g * 4) = o;
      }
    }
  }
}

// ---------- launch ----------
extern "C" void kernel_launch(void* const* d_in, const int* in_sizes, int n_in,
                              void* d_out, int out_size, void* d_ws, size_t ws_size,
                              hipStream_t stream) {
  const float* h   = (const float*)d_in[0];
  const float* x   = (const float*)d_in[1];
  const int*   ei  = (const int*)d_in[2];
  const int*   mask= (const int*)d_in[3];
  const float* wq  = (const float*)d_in[4];
  const float* bq  = (const float*)d_in[5];
  const float* wk  = (const float*)d_in[6];
  const float* bk  = (const float*)d_in[7];
  const float* wv  = (const float*)d_in[8];
  const float* bv  = (const float*)d_in[9];
  const float* wo  = (const float*)d_in[10];
  const float* bo  = (const float*)d_in[11];
  const float* pw1 = (const float*)d_in[12];
  const float* pb1 = (const float*)d_in[13];
  const float* pw2 = (const float*)d_in[14];
  const float* pb2 = (const float*)d_in[15];
  const float* ew1 = (const float*)d_in[16];
  const float* eb1 = (const float*)d_in[17];
  const float* ew2 = (const float*)d_in[18];
  const float* eb2 = (const float*)d_in[19];
  const float* eww = (const float*)d_in[20];
  const float* ewb = (const float*)d_in[21];
  const float* cw1 = (const float*)d_in[22];
  const float* cb1 = (const float*)d_in[23];
  const float* cw2 = (const float*)d_in[24];
  const float* cb2 = (const float*)d_in[25];
  const float* cw3 = (const float*)d_in[26];
  const float* cb3 = (const float*)d_in[27];

  int n = in_sizes[0] / 128;
  int E = in_sizes[3];

  char* wptr = (char*)d_ws;
  auto alloc = [&](size_t bytes) {
    char* p = wptr;
    wptr += (bytes + 255) & ~(size_t)255;
    return p;
  };
  ushort* q_t   = (ushort*)alloc((size_t)n * 512 * 2);
  uchar*  k8    = (uchar*)alloc((size_t)n * 512);
  ushort* v_t   = (ushort*)alloc((size_t)n * 512 * 2);
  ushort* h_bf  = (ushort*)alloc((size_t)n * 128 * 2);
  float* scores = (float*)alloc((size_t)E * 8 * 4);
  ushort* agg   = (ushort*)alloc((size_t)n * 512 * 2);
  ushort* c1    = (ushort*)alloc((size_t)n * 256 * 2);
  ushort* c2    = (ushort*)alloc((size_t)n * 256 * 2);
  ushort* wqkv  = (ushort*)alloc((size_t)1536 * 128 * 2);
  float* bqkv   = (float*)alloc((size_t)1536 * 4);
  short* W1T    = (short*)alloc((size_t)512 * 288 * 2);
  float* b1big  = (float*)alloc((size_t)512 * 4);
  short* W2T    = (short*)alloc((size_t)16 * 512 * 2);
  float* biasC  = (float*)alloc((size_t)16 * 4);
  ushort* wcomb = (ushort*)alloc((size_t)128 * 768 * 2);
  float* bcomb  = (float*)alloc((size_t)128 * 4);
  ushort* cw2bf = (ushort*)alloc((size_t)256 * 256 * 2);
  int* offs     = (int*)alloc((size_t)(n + 1) * 4);
  int* cursor   = (int*)alloc((size_t)n * 4);
  int2* pairs   = (int2*)alloc((size_t)E * 8);

  hipMemsetAsync(cursor, 0, (size_t)n * 4, stream);

  // mega-prep segment boundaries
  int b_h2  = (n * 128 / 4 + 255) / 256;
  int b_c1  = (n * 256 + 255) / 256;
  int b_wq  = (1536 * 128 + 255) / 256;
  int b_w1  = (512 * 288 + 255) / 256;
  int b_w2  = (16 * 512 + 255) / 256;
  int b_wc  = (128 * 768 + 255) / 256;
  int b_cw  = (256 * 256 + 255) / 256;
  int b_cnt = (E + 255) / 256;
  int o1 = b_h2, o2 = o1 + b_c1, o3 = o2 + b_wq, o4 = o3 + b_w1;
  int o5 = o4 + b_w2, o6 = o5 + b_wc, o7 = o6 + b_cw;
  int total_blocks = o7 + b_cnt;

  mega_prep<<<dim3(total_blocks), 256, 0, stream>>>(
      h, x, ei, wq, wk, wv, bq, bk, bv, ew1, eb1, pw1, pb1, ew2, eww, eb2, ewb,
      pw2, pb2, wo, cw3, bo, cb3, cw1, cb1, cw2,
      h_bf, c1, wqkv, bqkv, W1T, b1big, W2T, biasC, wcomb, bcomb, cw2bf, cursor,
      n, E, o1, o2, o3, o4, o5, o6, o7);

  scan_kernel<<<dim3(1), 1024, 0, stream>>>(cursor, offs, n);
  fill_kernel<<<dim3((E + 255) / 256), 256, 0, stream>>>(ei, cursor, pairs, E);

  qkv_mfma2_kernel<<<dim3((n + 63) / 64), 256, 0, stream>>>(h_bf, wqkv, bqkv, q_t, k8, v_t, n);

  edge_mfma2_kernel<<<dim3((E + EB - 1) / EB), 256, 0, stream>>>(
      h_bf, x, ei, E, W1T, b1big, W2T, biasC, scores);

  attn_fused_kernel<<<dim3((n + 3) / 4), 256, 0, stream>>>(
      offs, pairs, mask, scores, q_t, k8, v_t, agg, n);

  c2_mfma_kernel<<<dim3((n + 63) / 64, 4), 256, 0, stream>>>(c1, cw2bf, cb2, c2, n);

  hipMemsetAsync((float*)d_out + (size_t)n * 128, 0, (size_t)n * 3 * 4, stream);
  final_mfma_kernel<<<dim3((n + 63) / 64, 2), 256, 0, stream>>>(agg, c2, wcomb, bcomb,
                                                                (float*)d_out, n);
}

// Round 6
// 620.815 us; speedup vs baseline: 6.4649x; 1.1292x over previous
//
#include <hip/hip_runtime.h>

typedef unsigned int uint;
typedef unsigned short ushort;
typedef unsigned char uchar;
typedef __attribute__((ext_vector_type(8))) short bf16x8;
typedef __attribute__((ext_vector_type(8))) ushort ushort8;
typedef __attribute__((ext_vector_type(4))) float f32x4;

// ---------- helpers ----------
__device__ __forceinline__ float silu_fast(float t) {
  return t * __builtin_amdgcn_rcpf(1.f + __expf(-t));
}
__device__ __forceinline__ float bf2f(ushort u) {
  union { uint i; float f; } v; v.i = ((uint)u) << 16; return v.f;
}
__device__ __forceinline__ float bf2f_lo(uint u) {
  union { uint i; float f; } v; v.i = u << 16; return v.f;
}
__device__ __forceinline__ float bf2f_hi(uint u) {
  union { uint i; float f; } v; v.i = u & 0xffff0000u; return v.f;
}
__device__ __forceinline__ ushort f2bf(float f) {
  union { float f; uint i; } v; v.f = f;
  uint r = (v.i + 0x7fffu + ((v.i >> 16) & 1u)) >> 16;
  return (ushort)r;
}
__device__ __forceinline__ uint cvtpk_bf(float a, float b) {
  uint r; asm("v_cvt_pk_bf16_f32 %0, %1, %2" : "=v"(r) : "v"(a), "v"(b)); return r;
}
// fp8 e4m3 (OCP) encode, RNE, sat-to-448
__device__ __forceinline__ uchar f2e4m3(float f) {
  uint u = __float_as_uint(f);
  uint s = (u >> 24) & 0x80u;
  uint m = u & 0x7fffffffu;
  if (m >= 0x43f00000u) return (uchar)(s | 0x7e);
  if (m >= 0x3c800000u) {
    uint r = m + 0x7ffffu + ((m >> 20) & 1u);
    uint e = (r >> 23) - 120u;
    if (e > 15u) return (uchar)(s | 0x7e);
    return (uchar)(s | (e << 3) | ((r >> 20) & 7u));
  }
  float az = __uint_as_float(m);
  uint k = (uint)__float2int_rn(az * 512.f);
  return (uchar)(s | k);
}
__device__ __forceinline__ float e4m3f(uint b) {
  uint u = ((b & 0x80u) << 24) | ((b & 0x7fu) << 20);
  return __uint_as_float(u) * 0x1p+120f;
}

// ---------- mega prep: c1 | wnode | W1g | W2T | wcomb | cw2bf | count ----------
__global__ __launch_bounds__(256) void mega_prep(
    const float* __restrict__ x, const int* __restrict__ ei,
    const float* __restrict__ wq, const float* __restrict__ wk, const float* __restrict__ wv,
    const float* __restrict__ bq, const float* __restrict__ bk, const float* __restrict__ bv,
    const float* __restrict__ ew1, const float* __restrict__ eb1,
    const float* __restrict__ pw1, const float* __restrict__ pb1,
    const float* __restrict__ ew2, const float* __restrict__ eww,
    const float* __restrict__ eb2, const float* __restrict__ ewb,
    const float* __restrict__ pw2, const float* __restrict__ pb2,
    const float* __restrict__ wo, const float* __restrict__ cw3,
    const float* __restrict__ bo, const float* __restrict__ cb3,
    const float* __restrict__ cw1, const float* __restrict__ cb1,
    const float* __restrict__ cw2,
    ushort* __restrict__ c1,
    ushort* __restrict__ wnode, float* __restrict__ bqkv,
    short* __restrict__ W1g,
    short* __restrict__ W2T, float* __restrict__ biasC,
    ushort* __restrict__ wcomb, float* __restrict__ bcomb,
    ushort* __restrict__ cw2bf, int* __restrict__ cnt,
    int n, int E,
    int o1, int o2, int o3, int o4, int o5, int o6)
{
  int b = blockIdx.x, tid = threadIdx.x;
  if (b < o1) {                       // c1 = silu(x@cw1^T+cb1) bf16
    int idx = b * 256 + tid;
    if (idx < n * 256) {
      int node = idx >> 8, j = idx & 255;
      float t = fmaf(x[node * 3 + 2], cw1[j * 3 + 2],
                fmaf(x[node * 3 + 1], cw1[j * 3 + 1],
                fmaf(x[node * 3 + 0], cw1[j * 3 + 0], cb1[j])));
      c1[idx] = f2bf(silu_fast(t));
    }
  } else if (b < o2) {                // wnode [2048][128] bf16 + bqkv
    int idx = (b - o1) * 256 + tid;
    if (idx < 2048 * 128) {
      int j = idx >> 7, k = idx & 127;
      float v;
      if (j < 512)       v = wq[j * 128 + k];
      else if (j < 1024) v = wk[(j - 512) * 128 + k];
      else if (j < 1536) v = wv[(j - 1024) * 128 + k];
      else if (j < 1792) v = ew1[(j - 1536) * 263 + k];
      else               v = ew1[(j - 1792) * 263 + 128 + k];
      wnode[idx] = f2bf(v);
      if (idx < 1536)
        bqkv[idx] = (idx < 512) ? bq[idx] : (idx < 1024) ? bk[idx - 512] : bv[idx - 1024];
    }
  } else if (b < o3) {                // W1g [512 n][32 k]: geom+bias projection
    int idx = (b - o2) * 256 + tid;
    if (idx < 512 * 32) {
      int nn = idx >> 5, k = idx & 31;
      float v = 0.f;
      if (nn < 256) {
        if (k == 0)      v = eb1[nn];
        else if (k < 8)  v = ew1[nn * 263 + 256 + (k - 1)];   // rd, xr(3), xc(3)
      } else {
        int p = nn - 256;
        if (k == 0)           v = pb1[p];
        else if (k >= 2 && k < 8) v = pw1[p * 6 + (k - 2)];   // xr(3), xc(3)
      }
      W1g[idx] = (short)f2bf(v);
    }
  } else if (b < o4) {                // W2T [16][512] + biasC
    int idx = (b - o3) * 256 + tid;
    if (idx < 16 * 512) {
      int hh = idx >> 9, k = idx & 511;
      float v = 0.f;
      if (hh < 8) {
        if (k < 256) {
          float s = 0.f;
          for (int j = 0; j < 256; ++j) s += eww[hh * 256 + j] * ew2[j * 256 + k];
          v = s;
        } else v = pw2[hh * 256 + (k - 256)];
      }
      W2T[idx] = (short)f2bf(v);
      if (idx < 16) {
        float bb = 0.f;
        if (idx < 8) {
          float s = 0.f;
          for (int j = 0; j < 256; ++j) s += eww[idx * 256 + j] * eb2[j];
          bb = s + ewb[idx] + pb2[idx];
        }
        biasC[idx] = bb;
      }
    }
  } else if (b < o5) {                // wcomb [128][768] + bcomb
    int idx = (b - o4) * 256 + tid;
    if (idx < 128 * 768) {
      int j = idx / 768, k = idx % 768;
      float v = (k < 512) ? wo[j * 512 + k] : cw3[j * 256 + (k - 512)];
      wcomb[idx] = f2bf(v);
      if (idx < 128) bcomb[idx] = bo[idx] + cb3[idx];
    }
  } else if (b < o6) {                // cw2 bf16
    int idx = (b - o5) * 256 + tid;
    if (idx < 256 * 256) cw2bf[idx] = f2bf(cw2[idx]);
  } else {                            // count (CSR degree)
    int e = (b - o6) * 256 + tid;
    if (e < E) atomicAdd(&cnt[ei[e]], 1);
  }
}

// ---------- node projections via swapped MFMA: q | k8 | v | P1 | P2 ----------
__global__ __launch_bounds__(256) void nodeproj_kernel(
    const float* __restrict__ h,        // [n][128] f32
    const ushort* __restrict__ wnode,   // [2048][128]
    const float* __restrict__ bqkv,     // [1536]
    ushort* __restrict__ q_t, uchar* __restrict__ k8, ushort* __restrict__ v_t,
    ushort* __restrict__ P1t, ushort* __restrict__ P2t,
    int n)
{
  int tid = threadIdx.x;
  int lane = tid & 63, w = tid >> 6;
  int l15 = lane & 15, l4 = lane >> 4;
  int m0 = blockIdx.x * 64;
  int jb0 = blockIdx.y * 8;
  int mrow = m0 + w * 16 + l15;
  bool valid = mrow < n;
  int mr = valid ? mrow : (n - 1);

  bf16x8 hf[4];
#pragma unroll
  for (int ks = 0; ks < 4; ++ks) {
    const float* hp = h + (size_t)mr * 128 + ks * 32 + l4 * 8;
    float4 a0 = *(const float4*)hp;
    float4 a1 = *(const float4*)(hp + 4);
    uint4 pk;
    pk.x = cvtpk_bf(a0.x, a0.y); pk.y = cvtpk_bf(a0.z, a0.w);
    pk.z = cvtpk_bf(a1.x, a1.y); pk.w = cvtpk_bf(a1.z, a1.w);
    union { uint4 u; bf16x8 b; } cv; cv.u = pk;
    hf[ks] = cv.b;
  }

  for (int jb = jb0; jb < jb0 + 8; ++jb) {
    f32x4 acc[4];
#pragma unroll
    for (int nf = 0; nf < 4; ++nf) acc[nf] = (f32x4){0.f, 0.f, 0.f, 0.f};
#pragma unroll
    for (int nf = 0; nf < 4; ++nf)
#pragma unroll
      for (int ks = 0; ks < 4; ++ks) {
        bf16x8 wf = *(const bf16x8*)(wnode + (size_t)(jb * 64 + nf * 16 + l15) * 128 + ks * 32 + l4 * 8);
        acc[nf] = __builtin_amdgcn_mfma_f32_16x16x32_bf16(wf, hf[ks], acc[nf], 0, 0, 0);
      }
    if (valid) {
#pragma unroll
      for (int nf = 0; nf < 4; ++nf) {
        int gc = jb * 64 + nf * 16 + l4 * 4;
        if (jb < 24) {
          float4 bb = *(const float4*)(bqkv + gc);
          float v0 = acc[nf][0] + bb.x, v1 = acc[nf][1] + bb.y;
          float v2 = acc[nf][2] + bb.z, v3 = acc[nf][3] + bb.w;
          if (jb < 8) {
            ushort4 st; st.x = f2bf(v0); st.y = f2bf(v1); st.z = f2bf(v2); st.w = f2bf(v3);
            *(ushort4*)(q_t + (size_t)mrow * 512 + gc) = st;
          } else if (jb < 16) {
            uint pk = (uint)f2e4m3(v0) | ((uint)f2e4m3(v1) << 8)
                    | ((uint)f2e4m3(v2) << 16) | ((uint)f2e4m3(v3) << 24);
            *(uint*)(k8 + (size_t)mrow * 512 + (gc - 512)) = pk;
          } else {
            ushort4 st; st.x = f2bf(v0); st.y = f2bf(v1); st.z = f2bf(v2); st.w = f2bf(v3);
            *(ushort4*)(v_t + (size_t)mrow * 512 + (gc - 1024)) = st;
          }
        } else {
          int pc = (jb & 3) * 64 + nf * 16 + l4 * 4;
          ushort4 st;
          st.x = f2bf(acc[nf][0]); st.y = f2bf(acc[nf][1]);
          st.z = f2bf(acc[nf][2]); st.w = f2bf(acc[nf][3]);
          if (jb < 28) *(ushort4*)(P1t + (size_t)mrow * 256 + pc) = st;
          else         *(ushort4*)(P2t + (size_t)mrow * 256 + pc) = st;
        }
      }
    }
  }
}

// ---------- CSR scan + fill ----------
__global__ __launch_bounds__(1024) void scan_kernel(int* __restrict__ cnt,
                                                    int* __restrict__ offs, int n) {
  __shared__ int part[1024];
  int t = threadIdx.x;
  int chunk = (n + 1023) >> 10;
  int s = t * chunk, e = min(s + chunk, n);
  int sum = 0;
  for (int i = s; i < e; ++i) sum += cnt[i];
  part[t] = sum;
  __syncthreads();
  for (int off = 1; off < 1024; off <<= 1) {
    int v = (t >= off) ? part[t - off] : 0;
    __syncthreads();
    part[t] += v;
    __syncthreads();
  }
  int run = (t == 0) ? 0 : part[t - 1];
  for (int i = s; i < e; ++i) {
    int c = cnt[i];
    offs[i] = run;
    cnt[i] = run;
    run += c;
  }
  if (t == 1023) offs[n] = run;
}

// pairs[slot] = (col, row | (masked ? 0x80000000 : 0))
__global__ __launch_bounds__(256) void fill_kernel(const int* __restrict__ ei,
                                                   const int* __restrict__ mask,
                                                   int* __restrict__ cursor,
                                                   int2* __restrict__ pairs, int E) {
  int e = blockIdx.x * 256 + threadIdx.x;
  if (e < E) {
    int r = ei[e];
    int p = atomicAdd(&cursor[r], 1);
    int rm = r | (mask[e] ? 0 : (int)0x80000000u);
    pairs[p] = make_int2(ei[E + e], rm);
  }
}

// ---------- edge MLP v3: factorized, CSR-ordered ----------
// t1[n<256] = G_mfma(geom,K=32 incl bias) + P1[r] + P2[c];  t1[n>=256] = pos_mfma
// scores[slot][8] = silu(t1) @ W2T + biasC   (pre-masked)
#define EB 64
#define GS 40       // geom stride (shorts): 80B rows, 16B aligned, 2-way banks
#define TS 72       // t1 stride (shorts)

__global__ __launch_bounds__(256) void edge_mfma3_kernel(
    const float* __restrict__ x,
    const int2* __restrict__ pairs, int E,
    const short* __restrict__ W1g,      // [512][32]
    const short* __restrict__ W2T, const float* __restrict__ biasC,
    const ushort* __restrict__ P1t, const ushort* __restrict__ P2t,
    float* __restrict__ scores)
{
  __shared__ short geomL[EB * GS];      // 5 KB
  __shared__ int2 rcL[EB];              // 0.5 KB
  __shared__ short T1[4 * EB * TS];     // 36,864 B
  float* slab = (float*)T1;             // overlay after layer2

  int tid = threadIdx.x;
  int lane = tid & 63, w = tid >> 6;
  int l15 = lane & 15, l4 = lane >> 4;
  int eb0 = blockIdx.x * EB;

  // ---- geom + rc staging (1 thread/edge) ----
  if (tid < EB) {
    int i = min(eb0 + tid, E - 1);
    int2 pr = pairs[i];
    rcL[tid] = pr;
    int c = pr.x, r = pr.y & 0x7fffffff;
    float xr0 = x[r*3], xr1 = x[r*3+1], xr2 = x[r*3+2];
    float xc0 = x[c*3], xc1 = x[c*3+1], xc2 = x[c*3+2];
    float d0 = xr0-xc0, d1 = xr1-xc1, d2 = xr2-xc2;
    bf16x8 g;
    g[0] = (short)0x3F80;               // 1.0 (bias input)
    g[1] = (short)f2bf(d0*d0 + d1*d1 + d2*d2);
    g[2] = (short)f2bf(xr0); g[3] = (short)f2bf(xr1); g[4] = (short)f2bf(xr2);
    g[5] = (short)f2bf(xc0); g[6] = (short)f2bf(xc1); g[7] = (short)f2bf(xc2);
    bf16x8 z = {0,0,0,0,0,0,0,0};
    *(bf16x8*)(geomL + tid * GS) = g;
    *(bf16x8*)(geomL + tid * GS + 8) = z;
    *(bf16x8*)(geomL + tid * GS + 16) = z;
    *(bf16x8*)(geomL + tid * GS + 24) = z;
    *(bf16x8*)(geomL + tid * GS + 32) = z;
  }
  __syncthreads();

  // per-lane edge rows for P gathers
  int rr[4], cc[4];
  bf16x8 bE[4];
#pragma unroll
  for (int ef = 0; ef < 4; ++ef) {
    int2 pr = rcL[ef * 16 + l15];
    cc[ef] = pr.x; rr[ef] = pr.y & 0x7fffffff;
    bE[ef] = *(const bf16x8*)(geomL + (ef * 16 + l15) * GS + l4 * 8);
  }

  f32x4 sacc[4];
#pragma unroll
  for (int ef = 0; ef < 4; ++ef) sacc[ef] = (f32x4){0.f, 0.f, 0.f, 0.f};

  short* t1w = T1 + w * (EB * TS);

#pragma unroll
  for (int cch = 0; cch < 2; ++cch) {
    const int n0 = cch ? (256 + w * 64) : (w * 64);
    f32x4 acc[4][4];
    // layer1: one K=32 MFMA per (mf,ef): geom @ W1g  (includes bias)
#pragma unroll
    for (int mf = 0; mf < 4; ++mf) {
      bf16x8 aW = *(const bf16x8*)(W1g + (size_t)(n0 + mf * 16 + l15) * 32 + l4 * 8);
#pragma unroll
      for (int ef = 0; ef < 4; ++ef)
        acc[mf][ef] = __builtin_amdgcn_mfma_f32_16x16x32_bf16(
            aW, bE[ef], (f32x4){0.f, 0.f, 0.f, 0.f}, 0, 0, 0);
    }
    // edge chunk: add gathered P1[r] + P2[c] (register gather, off MFMA path)
    if (cch == 0) {
#pragma unroll
      for (int mf = 0; mf < 4; ++mf) {
        int colb = n0 + mf * 16 + l4 * 4;
        uint2 g1[4], g2[4];
#pragma unroll
        for (int ef = 0; ef < 4; ++ef) {
          g1[ef] = *(const uint2*)(P1t + (size_t)rr[ef] * 256 + colb);
          g2[ef] = *(const uint2*)(P2t + (size_t)cc[ef] * 256 + colb);
        }
#pragma unroll
        for (int ef = 0; ef < 4; ++ef) {
          f32x4 a = acc[mf][ef];
          a[0] += bf2f_lo(g1[ef].x) + bf2f_lo(g2[ef].x);
          a[1] += bf2f_hi(g1[ef].x) + bf2f_hi(g2[ef].x);
          a[2] += bf2f_lo(g1[ef].y) + bf2f_lo(g2[ef].y);
          a[3] += bf2f_hi(g1[ef].y) + bf2f_hi(g2[ef].y);
          acc[mf][ef] = a;
        }
      }
    }
    // silu + pack -> t1 LDS
#pragma unroll
    for (int mf = 0; mf < 4; ++mf) {
      int nl = mf * 16 + l4 * 4;
#pragma unroll
      for (int ef = 0; ef < 4; ++ef) {
        int e = ef * 16 + l15;
        f32x4 v = acc[mf][ef];
        float s0 = silu_fast(v[0]);
        float s1 = silu_fast(v[1]);
        float s2 = silu_fast(v[2]);
        float s3 = silu_fast(v[3]);
        uint2 pk;
        pk.x = cvtpk_bf(s0, s1);
        pk.y = cvtpk_bf(s2, s3);
        *(uint2*)(t1w + e * TS + nl) = pk;
      }
    }
    // layer2 partial over this 64-col chunk
#pragma unroll
    for (int ks2 = 0; ks2 < 2; ++ks2) {
      bf16x8 bW2 = *(const bf16x8*)(W2T + (size_t)l15 * 512 + n0 + ks2 * 32 + l4 * 8);
#pragma unroll
      for (int ef = 0; ef < 4; ++ef) {
        bf16x8 aT = *(const bf16x8*)(t1w + (ef * 16 + l15) * TS + ks2 * 32 + l4 * 8);
        sacc[ef] = __builtin_amdgcn_mfma_f32_16x16x32_bf16(aT, bW2, sacc[ef], 0, 0, 0);
      }
    }
  }
  __syncthreads();    // all layer2 reads done; overlay slab on T1
#pragma unroll
  for (int ef = 0; ef < 4; ++ef)
#pragma unroll
    for (int i = 0; i < 4; ++i)
      slab[(w * EB + ef * 16 + l4 * 4 + i) * 16 + l15] = sacc[ef][i];
  __syncthreads();
  for (int t = tid; t < EB * 8; t += 256) {
    int e = t >> 3, hh = t & 7;
    float s = biasC[hh]
            + slab[(0 * EB + e) * 16 + hh] + slab[(1 * EB + e) * 16 + hh]
            + slab[(2 * EB + e) * 16 + hh] + slab[(3 * EB + e) * 16 + hh];
    if (rcL[e].y < 0) s = -1e9f;        // pre-masked
    if (eb0 + e < E) scores[(size_t)(eb0 + e) * 8 + hh] = s;
  }
}

// ---------- fused QK + softmax + aggregation ----------
__global__ __launch_bounds__(256) void attn_fused_kernel(
    const int* __restrict__ offs,
    const int2* __restrict__ pairs,
    const float* __restrict__ scores,   // CSR-ordered, pre-masked
    const ushort* __restrict__ q_t,
    const uchar* __restrict__ k8,
    const ushort* __restrict__ v_t,
    ushort* __restrict__ agg, int n)
{
  int node = blockIdx.x * 4 + (threadIdx.x >> 6);
  if (node >= n) return;
  int lane = threadIdx.x & 63;
  int start = offs[node], end = offs[node + 1];

  bf16x8 qv = *(const bf16x8*)(q_t + (size_t)node * 512 + lane * 8);
  float qf[8];
#pragma unroll
  for (int j = 0; j < 8; ++j) qf[j] = bf2f((ushort)qv[j]);

  float m = -3.0e38f, ssum = 0.f;
  float acc[8];
#pragma unroll
  for (int j = 0; j < 8; ++j) acc[j] = 0.f;

  if (start < end) {
    int col = pairs[start].x;
    uint2 kw = *(const uint2*)(k8 + (size_t)col * 512 + lane * 8);
    bf16x8 vv = *(const bf16x8*)(v_t + (size_t)col * 512 + lane * 8);
    float sml = scores[(size_t)start * 8 + (lane >> 3)];

    for (int i = start; i < end; ++i) {
      uint2 kwc = kw; bf16x8 vvc = vv; float smlc = sml;
      int inx = (i + 1 < end) ? (i + 1) : i;
      col = pairs[inx].x;
      kw = *(const uint2*)(k8 + (size_t)col * 512 + lane * 8);
      vv = *(const bf16x8*)(v_t + (size_t)col * 512 + lane * 8);
      sml = scores[(size_t)inx * 8 + (lane >> 3)];

      float dot = 0.f;
#pragma unroll
      for (int j = 0; j < 4; ++j)
        dot = fmaf(qf[j], e4m3f((kwc.x >> (8 * j)) & 0xffu), dot);
#pragma unroll
      for (int j = 0; j < 4; ++j)
        dot = fmaf(qf[4 + j], e4m3f((kwc.y >> (8 * j)) & 0xffu), dot);
      dot += __shfl_xor(dot, 1);
      dot += __shfl_xor(dot, 2);
      dot += __shfl_xor(dot, 4);
      float s = (smlc < -5e8f) ? -1e9f : fmaf(dot, 0.125f, smlc);
      float nm = fmaxf(m, s);
      float cs = __expf(m - nm);
      float e  = __expf(s - nm);
      ssum = fmaf(ssum, cs, e);
#pragma unroll
      for (int j = 0; j < 8; ++j)
        acc[j] = fmaf(acc[j], cs, e * bf2f((ushort)vvc[j]));
      m = nm;
    }
  }
  float inv = __builtin_amdgcn_rcpf(ssum + 1e-8f);
  ushort8 ov;
#pragma unroll
  for (int j = 0; j < 8; ++j) ov[j] = f2bf(acc[j] * inv);
  *(ushort8*)(agg + (size_t)node * 512 + lane * 8) = ov;
}

// ---------- coord layer 2 via MFMA: c2 = silu(c1 @ cw2^T + cb2) bf16 ----------
__global__ __launch_bounds__(256) void c2_mfma_kernel(const ushort* __restrict__ c1,
                                                      const ushort* __restrict__ cw2bf,
                                                      const float* __restrict__ cb2,
                                                      ushort* __restrict__ c2, int n) {
  __shared__ float oS[64 * 68];
  int tid = threadIdx.x;
  int lane = tid & 63, w = tid >> 6;
  int l15 = lane & 15, l4 = lane >> 4;
  int m0 = blockIdx.x * 64;
  int n0 = blockIdx.y * 64 + w * 16;

  f32x4 acc[4];
#pragma unroll
  for (int mf = 0; mf < 4; ++mf) acc[mf] = (f32x4){0.f, 0.f, 0.f, 0.f};
#pragma unroll
  for (int ks = 0; ks < 8; ++ks) {
    bf16x8 bW = *(const bf16x8*)(cw2bf + (size_t)(n0 + l15) * 256 + ks * 32 + l4 * 8);
#pragma unroll
    for (int mf = 0; mf < 4; ++mf) {
      int gr = m0 + mf * 16 + l15; if (gr >= n) gr = n - 1;
      bf16x8 aH = *(const bf16x8*)(c1 + (size_t)gr * 256 + ks * 32 + l4 * 8);
      acc[mf] = __builtin_amdgcn_mfma_f32_16x16x32_bf16(aH, bW, acc[mf], 0, 0, 0);
    }
  }
#pragma unroll
  for (int mf = 0; mf < 4; ++mf)
#pragma unroll
    for (int i = 0; i < 4; ++i)
      oS[(mf * 16 + l4 * 4 + i) * 68 + w * 16 + l15] = acc[mf][i];
  __syncthreads();
  {
    int row = tid >> 2, cs = (tid & 3) * 16;
    int gr = m0 + row;
    if (gr < n) {
      int gc = blockIdx.y * 64 + cs;
      ushort8 o0, o1;
#pragma unroll
      for (int j = 0; j < 8; ++j) o0[j] = f2bf(silu_fast(oS[row * 68 + cs + j] + cb2[gc + j]));
#pragma unroll
      for (int j = 0; j < 8; ++j) o1[j] = f2bf(silu_fast(oS[row * 68 + cs + 8 + j] + cb2[gc + 8 + j]));
      *(ushort8*)(c2 + (size_t)gr * 256 + gc) = o0;
      *(ushort8*)(c2 + (size_t)gr * 256 + gc + 8) = o1;
    }
  }
}

// ---------- final fused out GEMM: out[n][128] = [agg|c2] @ wcomb^T + bcomb ----------
__global__ __launch_bounds__(256) void final_mfma_kernel(const ushort* __restrict__ agg,
                                                         const ushort* __restrict__ c2,
                                                         const ushort* __restrict__ wcomb,
                                                         const float* __restrict__ bcomb,
                                                         float* __restrict__ out, int n) {
  __shared__ float oS[64 * 68];
  int tid = threadIdx.x;
  int lane = tid & 63, w = tid >> 6;
  int l15 = lane & 15, l4 = lane >> 4;
  int m0 = blockIdx.x * 64;
  int jb = blockIdx.y;
  int n0 = jb * 64 + w * 16;

  f32x4 acc[4];
#pragma unroll
  for (int mf = 0; mf < 4; ++mf) acc[mf] = (f32x4){0.f, 0.f, 0.f, 0.f};
#pragma unroll
  for (int ks = 0; ks < 24; ++ks) {
    bf16x8 bW = *(const bf16x8*)(wcomb + (size_t)(n0 + l15) * 768 + ks * 32 + l4 * 8);
#pragma unroll
    for (int mf = 0; mf < 4; ++mf) {
      int gr = m0 + mf * 16 + l15; if (gr >= n) gr = n - 1;
      const ushort* ap = (ks < 16) ? (agg + (size_t)gr * 512 + ks * 32)
                                   : (c2 + (size_t)gr * 256 + (ks - 16) * 32);
      bf16x8 aH = *(const bf16x8*)(ap + l4 * 8);
      acc[mf] = __builtin_amdgcn_mfma_f32_16x16x32_bf16(aH, bW, acc[mf], 0, 0, 0);
    }
  }
#pragma unroll
  for (int mf = 0; mf < 4; ++mf)
#pragma unroll
    for (int i = 0; i < 4; ++i)
      oS[(mf * 16 + l4 * 4 + i) * 68 + w * 16 + l15] = acc[mf][i];
  __syncthreads();
  {
    int row = tid >> 2, cs = (tid & 3) * 16;
    int gr = m0 + row;
    if (gr < n) {
      int gc = jb * 64 + cs;
#pragma unroll
      for (int g = 0; g < 4; ++g) {
        float4 o;
        o.x = oS[row * 68 + cs + g * 4 + 0] + bcomb[gc + g * 4 + 0];
        o.y = oS[row * 68 + cs + g * 4 + 1] + bcomb[gc + g * 4 + 1];
        o.z = oS[row * 68 + cs + g * 4 + 2] + bcomb[gc + g * 4 + 2];
        o.w = oS[row * 68 + cs + g * 4 + 3] + bcomb[gc + g * 4 + 3];
        *(float4*)(out + (size_t)gr * 128 + gc + g * 4) = o;
      }
    }
  }
}

// ---------- launch ----------
extern "C" void kernel_launch(void* const* d_in, const int* in_sizes, int n_in,
                              void* d_out, int out_size, void* d_ws, size_t ws_size,
                              hipStream_t stream) {
  const float* h   = (const float*)d_in[0];
  const float* x   = (const float*)d_in[1];
  const int*   ei  = (const int*)d_in[2];
  const int*   mask= (const int*)d_in[3];
  const float* wq  = (const float*)d_in[4];
  const float* bq  = (const float*)d_in[5];
  const float* wk  = (const float*)d_in[6];
  const float* bk  = (const float*)d_in[7];
  const float* wv  = (const float*)d_in[8];
  const float* bv  = (const float*)d_in[9];
  const float* wo  = (const float*)d_in[10];
  const float* bo  = (const float*)d_in[11];
  const float* pw1 = (const float*)d_in[12];
  const float* pb1 = (const float*)d_in[13];
  const float* pw2 = (const float*)d_in[14];
  const float* pb2 = (const float*)d_in[15];
  const float* ew1 = (const float*)d_in[16];
  const float* eb1 = (const float*)d_in[17];
  const float* ew2 = (const float*)d_in[18];
  const float* eb2 = (const float*)d_in[19];
  const float* eww = (const float*)d_in[20];
  const float* ewb = (const float*)d_in[21];
  const float* cw1 = (const float*)d_in[22];
  const float* cb1 = (const float*)d_in[23];
  const float* cw2 = (const float*)d_in[24];
  const float* cb2 = (const float*)d_in[25];
  const float* cw3 = (const float*)d_in[26];
  const float* cb3 = (const float*)d_in[27];

  int n = in_sizes[0] / 128;
  int E = in_sizes[3];

  char* wptr = (char*)d_ws;
  auto alloc = [&](size_t bytes) {
    char* p = wptr;
    wptr += (bytes + 255) & ~(size_t)255;
    return p;
  };
  ushort* q_t   = (ushort*)alloc((size_t)n * 512 * 2);   // also reused as agg
  uchar*  k8    = (uchar*)alloc((size_t)n * 512);
  ushort* v_t   = (ushort*)alloc((size_t)n * 512 * 2);
  ushort* P1t   = (ushort*)alloc((size_t)n * 256 * 2);
  ushort* P2t   = (ushort*)alloc((size_t)n * 256 * 2);
  float* scores = (float*)alloc((size_t)E * 8 * 4);
  ushort* c1    = (ushort*)alloc((size_t)n * 256 * 2);
  ushort* c2    = (ushort*)alloc((size_t)n * 256 * 2);
  ushort* wnode = (ushort*)alloc((size_t)2048 * 128 * 2);
  float* bqkv   = (float*)alloc((size_t)1536 * 4);
  short* W1g    = (short*)alloc((size_t)512 * 32 * 2);
  short* W2T    = (short*)alloc((size_t)16 * 512 * 2);
  float* biasC  = (float*)alloc((size_t)16 * 4);
  ushort* wcomb = (ushort*)alloc((size_t)128 * 768 * 2);
  float* bcomb  = (float*)alloc((size_t)128 * 4);
  ushort* cw2bf = (ushort*)alloc((size_t)256 * 256 * 2);
  int* offs     = (int*)alloc((size_t)(n + 1) * 4);
  int* cursor   = (int*)alloc((size_t)n * 4);
  int2* pairs   = (int2*)alloc((size_t)E * 8);
  ushort* agg   = q_t;    // overlay: attn reads q[node] before writing agg[node]

  hipMemsetAsync(cursor, 0, (size_t)n * 4, stream);

  // mega-prep segment boundaries
  int b_c1  = (n * 256 + 255) / 256;
  int b_wn  = (2048 * 128) / 256;
  int b_w1  = (512 * 32 + 255) / 256;
  int b_w2  = (16 * 512 + 255) / 256;
  int b_wc  = (128 * 768 + 255) / 256;
  int b_cw  = (256 * 256 + 255) / 256;
  int b_cnt = (E + 255) / 256;
  int o1 = b_c1, o2 = o1 + b_wn, o3 = o2 + b_w1, o4 = o3 + b_w2;
  int o5 = o4 + b_wc, o6 = o5 + b_cw;
  int total_blocks = o6 + b_cnt;

  mega_prep<<<dim3(total_blocks), 256, 0, stream>>>(
      x, ei, wq, wk, wv, bq, bk, bv, ew1, eb1, pw1, pb1, ew2, eww, eb2, ewb,
      pw2, pb2, wo, cw3, bo, cb3, cw1, cb1, cw2,
      c1, wnode, bqkv, W1g, W2T, biasC, wcomb, bcomb, cw2bf, cursor,
      n, E, o1, o2, o3, o4, o5, o6);

  scan_kernel<<<dim3(1), 1024, 0, stream>>>(cursor, offs, n);
  fill_kernel<<<dim3((E + 255) / 256), 256, 0, stream>>>(ei, mask, cursor, pairs, E);

  nodeproj_kernel<<<dim3((n + 63) / 64, 4), 256, 0, stream>>>(
      h, wnode, bqkv, q_t, k8, v_t, P1t, P2t, n);

  edge_mfma3_kernel<<<dim3((E + EB - 1) / EB), 256, 0, stream>>>(
      x, pairs, E, W1g, W2T, biasC, P1t, P2t, scores);

  attn_fused_kernel<<<dim3((n + 3) / 4), 256, 0, stream>>>(
      offs, pairs, scores, q_t, k8, v_t, agg, n);

  c2_mfma_kernel<<<dim3((n + 63) / 64, 4), 256, 0, stream>>>(c1, cw2bf, cb2, c2, n);

  hipMemsetAsync((float*)d_out + (size_t)n * 128, 0, (size_t)n * 3 * 4, stream);
  final_mfma_kernel<<<dim3((n + 63) / 64, 2), 256, 0, stream>>>(agg, c2, wcomb, bcomb,
                                                                (float*)d_out, n);
}